// Round 1
// baseline (394.888 us; speedup 1.0000x reference)
//
#include <hip/hip_runtime.h>
#include <hip/hip_bf16.h>

// Problem constants
#define B_  4
#define T_  2048
#define DM  1024
#define NH  16
#define DH  64
#define BT_ (B_*T_)    // 8192
#define F3  (3*DM)     // 3072

typedef unsigned short u16;
typedef float  f32x4  __attribute__((ext_vector_type(4)));
typedef short  short8 __attribute__((ext_vector_type(8)));
typedef __bf16 bf16x8 __attribute__((ext_vector_type(8)));
typedef unsigned short u16x8 __attribute__((ext_vector_type(8)));

__device__ __forceinline__ u16 f2b(float f){
  __hip_bfloat16 h = __float2bfloat16(f);
  return *reinterpret_cast<u16*>(&h);
}
__device__ __forceinline__ float b2f(u16 u){
  __hip_bfloat16 h;
  *reinterpret_cast<u16*>(&h) = u;
  return __bfloat162float(h);
}

__device__ __forceinline__ f32x4 mfma16(short8 a, short8 b, f32x4 c){
  return __builtin_amdgcn_mfma_f32_16x16x32_bf16((bf16x8)a, (bf16x8)b, c, 0, 0, 0);
}

// async global->LDS, 16B per lane; lds dest must be wave-uniform base (+lane*16 implicit)
__device__ __forceinline__ void gll16(const void* g, void* l){
  __builtin_amdgcn_global_load_lds((const __attribute__((address_space(1))) unsigned int*)g,
                                   (__attribute__((address_space(3))) unsigned int*)l,
                                   16, 0, 0);
}

// ---------------- f32 -> bf16 convert (8 elems/thread) ----------------
__global__ __launch_bounds__(256) void k_f2b(const float* __restrict__ in,
                                             u16* __restrict__ out, int n8){
  int i = blockIdx.x*256 + threadIdx.x;
  if (i >= n8) return;
  const float4* p = reinterpret_cast<const float4*>(in) + (size_t)i*2;
  float4 a = p[0], b = p[1];
  u16x8 r;
  r[0]=f2b(a.x); r[1]=f2b(a.y); r[2]=f2b(a.z); r[3]=f2b(a.w);
  r[4]=f2b(b.x); r[5]=f2b(b.y); r[6]=f2b(b.z); r[7]=f2b(b.w);
  *(reinterpret_cast<u16x8*>(out) + i) = r;
}

// ---------------- GEMM C = A * B^T  (A: MxK bf16, B: NxK bf16) ----------------
// 128x128 tile, BK=64, 256 threads (2x2 waves, each 64x64 out = 4x4 16x16 frags)
template<typename OUT>
__global__ __launch_bounds__(256, 2) void k_gemm_bt(const u16* __restrict__ A,
                                                    const u16* __restrict__ Bm,
                                                    OUT* __restrict__ C,
                                                    int M, int N, int K){
  __shared__ __attribute__((aligned(16))) u16 lA[128*64];
  __shared__ __attribute__((aligned(16))) u16 lB[128*64];

  int nbn = N >> 7;
  int nwg = gridDim.x;
  int bid = blockIdx.x;
  int wg = bid;
  if ((nwg & 7) == 0) { int q = nwg >> 3; wg = (bid & 7)*q + (bid >> 3); } // XCD swizzle
  int bm = wg / nbn, bn = wg % nbn;

  int tid = threadIdx.x, wv = tid >> 6, l = tid & 63;
  int lane16 = l & 15, lg = l >> 4;
  int wr = wv >> 1, wc = wv & 1;

  f32x4 acc[4][4] = {};

  const u16* pA = A + (size_t)(bm*128 + wv*8 + (l>>3))*K + (l&7)*8;
  const u16* pB = Bm + (size_t)(bn*128 + wv*8 + (l>>3))*K + (l&7)*8;
  char* lAb = (char*)lA + wv*1024;
  char* lBb = (char*)lB + wv*1024;

  int nk = K >> 6;
  for (int kt = 0; kt < nk; ++kt){
    const u16* gA = pA + kt*64;
    const u16* gB = pB + kt*64;
    #pragma unroll
    for (int c = 0; c < 4; ++c){
      gll16(gA + (size_t)c*32*K, lAb + c*4096);
      gll16(gB + (size_t)c*32*K, lBb + c*4096);
    }
    __syncthreads();
    #pragma unroll
    for (int kk = 0; kk < 2; ++kk){
      short8 am[4], bb[4];
      #pragma unroll
      for (int m = 0; m < 4; ++m)
        am[m] = *(const short8*)&lA[(wr*64 + m*16 + lane16)*64 + kk*32 + lg*8];
      #pragma unroll
      for (int n = 0; n < 4; ++n)
        bb[n] = *(const short8*)&lB[(wc*64 + n*16 + lane16)*64 + kk*32 + lg*8];
      #pragma unroll
      for (int m = 0; m < 4; ++m)
        #pragma unroll
        for (int n = 0; n < 4; ++n)
          acc[m][n] = mfma16(am[m], bb[n], acc[m][n]);
    }
    __syncthreads();
  }

  #pragma unroll
  for (int m = 0; m < 4; ++m){
    #pragma unroll
    for (int n = 0; n < 4; ++n){
      #pragma unroll
      for (int r = 0; r < 4; ++r){
        int grow = bm*128 + wr*64 + m*16 + lg*4 + r;
        int gcol = bn*128 + wc*64 + n*16 + lane16;
        float v = acc[m][n][r];
        if constexpr (sizeof(OUT) == 2) C[(size_t)grow*N + gcol] = (OUT)f2b(v);
        else                            C[(size_t)grow*N + gcol] = v;
      }
    }
  }
}

// ---------------- RoPE + head-split + V transpose ----------------
// grid (T/64, H, B), block 256. Writes Qh,Kh [BH][T][64] (Q pre-scaled 1/8),
// Vt [BH][64][T] via LDS transpose.
__global__ __launch_bounds__(256) void k_rope(const u16* __restrict__ qkv,
    const float* __restrict__ cosT, const float* __restrict__ sinT,
    u16* __restrict__ Qh, u16* __restrict__ Kh, u16* __restrict__ Vt){
  __shared__ float lsV[64][65];
  int t0 = blockIdx.x*64, h = blockIdx.y, b = blockIdx.z;
  int bh = b*NH + h;
  int i = threadIdx.x;
  int tl = i >> 2, dc = i & 3;
  int t = t0 + tl;
  size_t rowbase = (size_t)(b*T_ + t)*F3;
  int d0 = dc*8;

  float c1[8], s1[8], c2[8], s2[8];
  const float* cp = cosT + t*64 + d0;
  const float* sp = sinT + t*64 + d0;
  #pragma unroll
  for (int j=0;j<8;++j){ c1[j]=cp[j]; s1[j]=sp[j]; c2[j]=cp[32+j]; s2[j]=sp[32+j]; }

  #pragma unroll
  for (int qk = 0; qk < 2; ++qk){
    u16x8 u1 = *(const u16x8*)(qkv + rowbase + qk*DM + h*64 + d0);
    u16x8 u2 = *(const u16x8*)(qkv + rowbase + qk*DM + h*64 + d0 + 32);
    u16x8 o1, o2;
    float sc = (qk == 0) ? 0.125f : 1.0f;   // fold 1/sqrt(64) into Q
    #pragma unroll
    for (int j=0;j<8;++j){
      float a = b2f(u1[j]), bb = b2f(u2[j]);
      o1[j] = f2b((a*c1[j] - bb*s1[j])*sc);
      o2[j] = f2b((bb*c2[j] + a*s2[j])*sc);
    }
    u16* dst = (qk==0 ? Qh : Kh) + ((size_t)bh*T_ + t)*64 + d0;
    *(u16x8*)dst = o1;
    *(u16x8*)(dst + 32) = o2;
  }

  // V: load [t][d] tile, transpose through LDS, store [d][t]
  #pragma unroll
  for (int half = 0; half < 2; ++half){
    u16x8 v = *(const u16x8*)(qkv + rowbase + 2*DM + h*64 + dc*16 + half*8);
    #pragma unroll
    for (int j=0;j<8;++j) lsV[tl][dc*16 + half*8 + j] = b2f(v[j]);
  }
  __syncthreads();
  int dl = i >> 2, tc = i & 3;
  u16x8 w0, w1;
  #pragma unroll
  for (int j=0;j<8;++j){ w0[j] = f2b(lsV[tc*16+j][dl]); w1[j] = f2b(lsV[tc*16+8+j][dl]); }
  u16* vd = Vt + ((size_t)bh*64 + dl)*T_ + t0 + tc*16;
  *(u16x8*)vd = w0;
  *(u16x8*)(vd+8) = w1;
}

// ---------------- causal flash attention ----------------
// grid (T/64 [reversed], B*H), block 256 (4 waves). Wave w owns q rows [q0+16w, +16).
// K tile [64][64] and V tile (pre-transposed) [64 d][64 kv] staged via global_load_lds.
__global__ __launch_bounds__(256, 2) void k_attn(const u16* __restrict__ Qh,
    const u16* __restrict__ Kh, const u16* __restrict__ Vt, u16* __restrict__ AO){
  __shared__ __attribute__((aligned(16))) u16 lK[64*64];
  __shared__ __attribute__((aligned(16))) u16 lV[64*64];
  __shared__ __attribute__((aligned(16))) u16 lP[4][16*72];  // stride 72 to break conflicts

  int qt = (int)gridDim.x - 1 - (int)blockIdx.x;  // big work first
  int q0 = qt*64;
  int bh = blockIdx.y;
  int b = bh >> 4, h = bh & 15;
  int tid = threadIdx.x, wv = tid >> 6, l = tid & 63;
  int lane16 = l & 15, lg = l >> 4;

  short8 aq[2];
  const u16* qp = Qh + ((size_t)bh*T_ + q0 + wv*16 + lane16)*64 + lg*8;
  aq[0] = *(const short8*)qp;
  aq[1] = *(const short8*)(qp + 32);

  f32x4 o[4] = {};
  float mrow[4] = {-INFINITY,-INFINITY,-INFINITY,-INFINITY};
  float lsum[4] = {0.f,0.f,0.f,0.f};

  const u16* Kb = Kh + (size_t)bh*T_*64;
  const u16* Vb = Vt + (size_t)bh*64*T_;

  int nt = qt + 1;
  for (int it = 0; it < nt; ++it){
    int kv0 = it*64;
    {
      int rloc = wv*8 + (l>>3);
      int cb = (l&7)*8;
      #pragma unroll
      for (int c = 0; c < 2; ++c){
        gll16(Kb + (size_t)(kv0 + rloc + c*32)*64 + cb, (char*)lK + wv*1024 + c*4096);
        gll16(Vb + (size_t)(rloc + c*32)*T_ + kv0 + cb, (char*)lV + wv*1024 + c*4096);
      }
    }
    __syncthreads();

    // S = Q K^T (scale folded into Q)
    f32x4 s[4];
    #pragma unroll
    for (int n = 0; n < 4; ++n){
      short8 bk0 = *(const short8*)&lK[(n*16 + lane16)*64 + lg*8];
      short8 bk1 = *(const short8*)&lK[(n*16 + lane16)*64 + 32 + lg*8];
      f32x4 z = {};
      z = mfma16(aq[0], bk0, z);
      z = mfma16(aq[1], bk1, z);
      s[n] = z;
    }

    if (it == nt-1){  // only the diagonal tile needs masking
      #pragma unroll
      for (int n = 0; n < 4; ++n){
        int key = kv0 + n*16 + lane16;
        #pragma unroll
        for (int r = 0; r < 4; ++r){
          int qrow = q0 + wv*16 + lg*4 + r;
          if (key > qrow) s[n][r] = -1e30f;
        }
      }
    }

    // online softmax: rows live in 16-lane groups (C/D layout: row=(l>>4)*4+r, col=l&15)
    #pragma unroll
    for (int r = 0; r < 4; ++r){
      float mx = fmaxf(fmaxf(s[0][r], s[1][r]), fmaxf(s[2][r], s[3][r]));
      #pragma unroll
      for (int off = 1; off < 16; off <<= 1) mx = fmaxf(mx, __shfl_xor(mx, off, 64));
      float mn = fmaxf(mrow[r], mx);
      float al = __expf(mrow[r] - mn);
      mrow[r] = mn;
      float rs = 0.f;
      #pragma unroll
      for (int n = 0; n < 4; ++n){ float p = __expf(s[n][r] - mn); s[n][r] = p; rs += p; }
      #pragma unroll
      for (int off = 1; off < 16; off <<= 1) rs += __shfl_xor(rs, off, 64);
      lsum[r] = lsum[r]*al + rs;
      #pragma unroll
      for (int dn = 0; dn < 4; ++dn) o[dn][r] *= al;
    }

    // P -> LDS (bf16), per-wave private buffer, then read as MFMA A-fragments
    #pragma unroll
    for (int n = 0; n < 4; ++n)
      #pragma unroll
      for (int r = 0; r < 4; ++r)
        lP[wv][(lg*4 + r)*72 + n*16 + lane16] = f2b(s[n][r]);
    asm volatile("s_waitcnt lgkmcnt(0)" ::: "memory");

    short8 pa0 = *(const short8*)&lP[wv][lane16*72 + lg*8];
    short8 pa1 = *(const short8*)&lP[wv][lane16*72 + 32 + lg*8];
    #pragma unroll
    for (int dn = 0; dn < 4; ++dn){
      short8 bv0 = *(const short8*)&lV[(dn*16 + lane16)*64 + lg*8];
      short8 bv1 = *(const short8*)&lV[(dn*16 + lane16)*64 + 32 + lg*8];
      o[dn] = mfma16(pa0, bv0, o[dn]);
      o[dn] = mfma16(pa1, bv1, o[dn]);
    }
    __syncthreads();
  }

  #pragma unroll
  for (int r = 0; r < 4; ++r){
    float inv = 1.f / lsum[r];
    int t = q0 + wv*16 + lg*4 + r;
    #pragma unroll
    for (int dn = 0; dn < 4; ++dn)
      AO[((size_t)(b*T_ + t))*DM + h*64 + dn*16 + lane16] = f2b(o[dn][r]*inv);
  }
}

// ---------------- launch ----------------
extern "C" void kernel_launch(void* const* d_in, const int* in_sizes, int n_in,
                              void* d_out, int out_size, void* d_ws, size_t ws_size,
                              hipStream_t stream) {
  const float* x     = (const float*)d_in[0];
  const float* cosT  = (const float*)d_in[1];
  const float* sinT  = (const float*)d_in[2];
  const float* w_qkv = (const float*)d_in[3];
  const float* w_out = (const float*)d_in[4];
  float* out = (float*)d_out;

  char* ws = (char*)d_ws;
  u16* xb    = (u16*)(ws);                      // 16 MB   (8192x1024)
  u16* wqkvb = (u16*)(ws + 16777216);           // 6 MB    (3072x1024)
  u16* woutb = (u16*)(ws + 23068672);           // 2 MB    (1024x1024)
  u16* qkv   = (u16*)(ws + 25165824);           // 48 MB   (8192x3072)
  u16* Kh    = (u16*)(ws + 75497472);           // 16 MB
  u16* Vt    = (u16*)(ws + 92274688);           // 16 MB -> total 104 MB
  u16* Qh = xb;    // alias: x_bf16 dead after QKV GEMM
  u16* AO = qkv;   // alias: qkv dead after rope/reshape

  // 1) convert inputs to bf16
  k_f2b<<<4096, 256, 0, stream>>>(x,     xb,    BT_*DM/8);
  k_f2b<<<1536, 256, 0, stream>>>(w_qkv, wqkvb, F3*DM/8);
  k_f2b<<<512,  256, 0, stream>>>(w_out, woutb, DM*DM/8);

  // 2) qkv = x @ w_qkv^T   (8192x3072)
  k_gemm_bt<u16><<<(BT_/128)*(F3/128), 256, 0, stream>>>(xb, wqkvb, qkv, BT_, F3, DM);

  // 3) RoPE + head split + V transpose
  k_rope<<<dim3(T_/64, NH, B_), 256, 0, stream>>>(qkv, cosT, sinT, Qh, Kh, Vt);

  // 4) causal flash attention -> AO [B,T,DM] bf16
  k_attn<<<dim3(T_/64, B_*NH), 256, 0, stream>>>(Qh, Kh, Vt, AO);

  // 5) out = AO @ w_out^T  (f32 out)
  k_gemm_bt<float><<<(BT_/128)*(DM/128), 256, 0, stream>>>(AO, woutb, out, BT_, DM, DM);
}

// Round 2
// 296.413 us; speedup vs baseline: 1.3322x; 1.3322x over previous
//
#include <hip/hip_runtime.h>
#include <hip/hip_bf16.h>

// Problem constants
#define B_  4
#define T_  2048
#define DM  1024
#define NH  16
#define DH  64
#define BT_ (B_*T_)    // 8192
#define F3  (3*DM)     // 3072

typedef unsigned short u16;
typedef float  f32x4  __attribute__((ext_vector_type(4)));
typedef short  short8 __attribute__((ext_vector_type(8)));
typedef __bf16 bf16x8 __attribute__((ext_vector_type(8)));
typedef unsigned short u16x8 __attribute__((ext_vector_type(8)));

__device__ __forceinline__ u16 f2b(float f){
  __hip_bfloat16 h = __float2bfloat16(f);
  return *reinterpret_cast<u16*>(&h);
}
__device__ __forceinline__ float b2f(u16 u){
  __hip_bfloat16 h;
  *reinterpret_cast<u16*>(&h) = u;
  return __bfloat162float(h);
}

__device__ __forceinline__ f32x4 mfma16(short8 a, short8 b, f32x4 c){
  return __builtin_amdgcn_mfma_f32_16x16x32_bf16((bf16x8)a, (bf16x8)b, c, 0, 0, 0);
}

// async global->LDS, 16B per lane; lds dest must be wave-uniform base (+lane*16 implicit)
__device__ __forceinline__ void gll16(const void* g, void* l){
  __builtin_amdgcn_global_load_lds((const __attribute__((address_space(1))) unsigned int*)g,
                                   (__attribute__((address_space(3))) unsigned int*)l,
                                   16, 0, 0);
}

// ---------------- f32 -> bf16 convert (8 elems/thread) ----------------
__global__ __launch_bounds__(256) void k_f2b(const float* __restrict__ in,
                                             u16* __restrict__ out, int n8){
  int i = blockIdx.x*256 + threadIdx.x;
  if (i >= n8) return;
  const float4* p = reinterpret_cast<const float4*>(in) + (size_t)i*2;
  float4 a = p[0], b = p[1];
  u16x8 r;
  r[0]=f2b(a.x); r[1]=f2b(a.y); r[2]=f2b(a.z); r[3]=f2b(a.w);
  r[4]=f2b(b.x); r[5]=f2b(b.y); r[6]=f2b(b.z); r[7]=f2b(b.w);
  *(reinterpret_cast<u16x8*>(out) + i) = r;
}

// ---------------- GEMM C = A * B^T  (A: MxK bf16, B: NxK bf16) ----------------
// 128x128 tile, BK=64, 256 threads (2x2 waves, each 64x64 out = 4x4 16x16 frags)
template<typename OUT>
__global__ __launch_bounds__(256, 2) void k_gemm_bt(const u16* __restrict__ A,
                                                    const u16* __restrict__ Bm,
                                                    OUT* __restrict__ C,
                                                    int M, int N, int K){
  __shared__ __attribute__((aligned(16))) u16 lA[128*64];
  __shared__ __attribute__((aligned(16))) u16 lB[128*64];

  int nbn = N >> 7;
  int nwg = gridDim.x;
  int bid = blockIdx.x;
  int wg = bid;
  if ((nwg & 7) == 0) { int q = nwg >> 3; wg = (bid & 7)*q + (bid >> 3); } // XCD swizzle
  int bm = wg / nbn, bn = wg % nbn;

  int tid = threadIdx.x, wv = tid >> 6, l = tid & 63;
  int lane16 = l & 15, lg = l >> 4;
  int wr = wv >> 1, wc = wv & 1;

  f32x4 acc[4][4] = {};

  const u16* pA = A + (size_t)(bm*128 + wv*8 + (l>>3))*K + (l&7)*8;
  const u16* pB = Bm + (size_t)(bn*128 + wv*8 + (l>>3))*K + (l&7)*8;
  char* lAb = (char*)lA + wv*1024;
  char* lBb = (char*)lB + wv*1024;

  int nk = K >> 6;
  for (int kt = 0; kt < nk; ++kt){
    const u16* gA = pA + kt*64;
    const u16* gB = pB + kt*64;
    #pragma unroll
    for (int c = 0; c < 4; ++c){
      gll16(gA + (size_t)c*32*K, lAb + c*4096);
      gll16(gB + (size_t)c*32*K, lBb + c*4096);
    }
    __syncthreads();
    #pragma unroll
    for (int kk = 0; kk < 2; ++kk){
      short8 am[4], bb[4];
      #pragma unroll
      for (int m = 0; m < 4; ++m)
        am[m] = *(const short8*)&lA[(wr*64 + m*16 + lane16)*64 + kk*32 + lg*8];
      #pragma unroll
      for (int n = 0; n < 4; ++n)
        bb[n] = *(const short8*)&lB[(wc*64 + n*16 + lane16)*64 + kk*32 + lg*8];
      #pragma unroll
      for (int m = 0; m < 4; ++m)
        #pragma unroll
        for (int n = 0; n < 4; ++n)
          acc[m][n] = mfma16(am[m], bb[n], acc[m][n]);
    }
    __syncthreads();
  }

  #pragma unroll
  for (int m = 0; m < 4; ++m){
    #pragma unroll
    for (int n = 0; n < 4; ++n){
      #pragma unroll
      for (int r = 0; r < 4; ++r){
        int grow = bm*128 + wr*64 + m*16 + lg*4 + r;
        int gcol = bn*128 + wc*64 + n*16 + lane16;
        float v = acc[m][n][r];
        if constexpr (sizeof(OUT) == 2) C[(size_t)grow*N + gcol] = (OUT)f2b(v);
        else                            C[(size_t)grow*N + gcol] = v;
      }
    }
  }
}

// ---------------- RoPE + head-split + V transpose ----------------
__global__ __launch_bounds__(256) void k_rope(const u16* __restrict__ qkv,
    const float* __restrict__ cosT, const float* __restrict__ sinT,
    u16* __restrict__ Qh, u16* __restrict__ Kh, u16* __restrict__ Vt){
  __shared__ float lsV[64][65];
  int t0 = blockIdx.x*64, h = blockIdx.y, b = blockIdx.z;
  int bh = b*NH + h;
  int i = threadIdx.x;
  int tl = i >> 2, dc = i & 3;
  int t = t0 + tl;
  size_t rowbase = (size_t)(b*T_ + t)*F3;
  int d0 = dc*8;

  float c1[8], s1[8], c2[8], s2[8];
  const float* cp = cosT + t*64 + d0;
  const float* sp = sinT + t*64 + d0;
  #pragma unroll
  for (int j=0;j<8;++j){ c1[j]=cp[j]; s1[j]=sp[j]; c2[j]=cp[32+j]; s2[j]=sp[32+j]; }

  #pragma unroll
  for (int qk = 0; qk < 2; ++qk){
    u16x8 u1 = *(const u16x8*)(qkv + rowbase + qk*DM + h*64 + d0);
    u16x8 u2 = *(const u16x8*)(qkv + rowbase + qk*DM + h*64 + d0 + 32);
    u16x8 o1, o2;
    float sc = (qk == 0) ? 0.125f : 1.0f;   // fold 1/sqrt(64) into Q
    #pragma unroll
    for (int j=0;j<8;++j){
      float a = b2f(u1[j]), bb = b2f(u2[j]);
      o1[j] = f2b((a*c1[j] - bb*s1[j])*sc);
      o2[j] = f2b((bb*c2[j] + a*s2[j])*sc);
    }
    u16* dst = (qk==0 ? Qh : Kh) + ((size_t)bh*T_ + t)*64 + d0;
    *(u16x8*)dst = o1;
    *(u16x8*)(dst + 32) = o2;
  }

  // V: load [t][d] tile, transpose through LDS, store [d][t]
  #pragma unroll
  for (int half = 0; half < 2; ++half){
    u16x8 v = *(const u16x8*)(qkv + rowbase + 2*DM + h*64 + dc*16 + half*8);
    #pragma unroll
    for (int j=0;j<8;++j) lsV[tl][dc*16 + half*8 + j] = b2f(v[j]);
  }
  __syncthreads();
  int dl = i >> 2, tc = i & 3;
  u16x8 w0, w1;
  #pragma unroll
  for (int j=0;j<8;++j){ w0[j] = f2b(lsV[tc*16+j][dl]); w1[j] = f2b(lsV[tc*16+8+j][dl]); }
  u16* vd = Vt + ((size_t)bh*64 + dl)*T_ + t0 + tc*16;
  *(u16x8*)vd = w0;
  *(u16x8*)(vd+8) = w1;
}

// ---------------- causal flash attention (swapped QK^T, swizzled LDS, dbuf) ----------------
// grid (T/64 [reversed], B*H), block 256 (4 waves). Wave w owns q rows [q0+16w, +16).
// LDS K/V tiles are chunk-XOR swizzled: LDS(row, chunk c) holds global(row, c ^ (row&7)),
// achieved by pre-swizzling the global_load_lds SOURCE (dest stays linear).
#define PSTR 68
__global__ __launch_bounds__(256, 2) void k_attn(const u16* __restrict__ Qh,
    const u16* __restrict__ Kh, const u16* __restrict__ Vt, u16* __restrict__ AO){
  __shared__ __attribute__((aligned(16))) u16 lK[2][64*64];
  __shared__ __attribute__((aligned(16))) u16 lV[2][64*64];
  __shared__ __attribute__((aligned(16))) u16 lP[4][16*PSTR];

  int qt = (int)gridDim.x - 1 - (int)blockIdx.x;  // big work first
  int q0 = qt*64;
  int bh = blockIdx.y;
  int b = bh >> 4, h = bh & 15;
  int tid = threadIdx.x, wv = tid >> 6, l = tid & 63;
  int lane16 = l & 15, lg = l >> 4;

  // Q fragments (B-operand of swapped QK^T): lane holds Q[q0+wv*16+lane16][kk*32+lg*8 ..+8]
  short8 bq[2];
  const u16* qp = Qh + ((size_t)bh*T_ + q0 + wv*16 + lane16)*64 + lg*8;
  bq[0] = *(const short8*)qp;
  bq[1] = *(const short8*)(qp + 32);

  f32x4 o[4] = {};                       // o[dn][r]: q_local=lg*4+r, d=dn*16+lane16
  float mrow = -INFINITY, lsum = 0.f;    // softmax state for q = q0+wv*16+lane16

  const u16* Kb = Kh + (size_t)bh*T_*64;
  const u16* Vb = Vt + (size_t)bh*64*T_;

  int rl = l >> 3;                 // row within 8-row staging group
  int sc = ((l&7) ^ rl) * 8;       // pre-swizzled source column (elements)
  int nt = qt + 1;

  // prologue: stage tile 0 into buffer 0
  #pragma unroll
  for (int c = 0; c < 2; ++c){
    gll16(Kb + (size_t)(wv*8 + rl + c*32)*64 + sc, (char*)lK + wv*1024 + c*4096);
    gll16(Vb + (size_t)(wv*8 + rl + c*32)*T_ + sc, (char*)lV + wv*1024 + c*4096);
  }
  __syncthreads();

  for (int it = 0; it < nt; ++it){
    int cur = it & 1;
    int kv0 = it*64;

    if (it + 1 < nt){   // issue next tile's loads; latency hides under compute below
      int kv1 = kv0 + 64;
      #pragma unroll
      for (int c = 0; c < 2; ++c){
        gll16(Kb + (size_t)(kv1 + wv*8 + rl + c*32)*64 + sc,
              (char*)lK + (cur^1)*8192 + wv*1024 + c*4096);
        gll16(Vb + (size_t)(wv*8 + rl + c*32)*T_ + kv1 + sc,
              (char*)lV + (cur^1)*8192 + wv*1024 + c*4096);
      }
    }

    const char* Kc = (const char*)lK + cur*8192;
    const char* Vc = (const char*)lV + cur*8192;

    // S^T tile: s[n][r] = S[k = kv0+n*16+lg*4+r][q = lane16-row of this wave]
    f32x4 s[4];
    __builtin_amdgcn_s_setprio(1);
    #pragma unroll
    for (int n = 0; n < 4; ++n){
      int row = n*16 + lane16;
      short8 ak0 = *(const short8*)(Kc + row*128 + (((lg    ) ^ (row&7))<<4));
      short8 ak1 = *(const short8*)(Kc + row*128 + (((4 + lg) ^ (row&7))<<4));
      f32x4 z = {};
      z = mfma16(ak0, bq[0], z);
      z = mfma16(ak1, bq[1], z);
      s[n] = z;
    }
    __builtin_amdgcn_s_setprio(0);

    if (it == nt-1){  // only diagonal tile needs masking
      int q_abs = q0 + wv*16 + lane16;
      #pragma unroll
      for (int n = 0; n < 4; ++n)
        #pragma unroll
        for (int r = 0; r < 4; ++r){
          int key = kv0 + n*16 + lg*4 + r;
          if (key > q_abs) s[n][r] = -1e30f;
        }
    }

    // online softmax: lane owns 16 of 64 scores for its q; row spread over lanes ^16,^32
    float pm = s[0][0];
    #pragma unroll
    for (int n = 0; n < 4; ++n)
      #pragma unroll
      for (int r = 0; r < 4; ++r) pm = fmaxf(pm, s[n][r]);
    pm = fmaxf(pm, __shfl_xor(pm, 16, 64));
    pm = fmaxf(pm, __shfl_xor(pm, 32, 64));
    float mn = fmaxf(mrow, pm);
    float al = __expf(mrow - mn);
    mrow = mn;
    float rs = 0.f;
    #pragma unroll
    for (int n = 0; n < 4; ++n)
      #pragma unroll
      for (int r = 0; r < 4; ++r){ float p = __expf(s[n][r] - mn); s[n][r] = p; rs += p; }
    rs += __shfl_xor(rs, 16, 64);
    rs += __shfl_xor(rs, 32, 64);
    lsum = lsum*al + rs;

    // broadcast rescale factor to the lanes holding o-rows q_local = lg*4+r
    float alr[4];
    #pragma unroll
    for (int r = 0; r < 4; ++r) alr[r] = __shfl(al, (l & 48) | (lg*4 + r), 64);
    #pragma unroll
    for (int dn = 0; dn < 4; ++dn)
      #pragma unroll
      for (int r = 0; r < 4; ++r) o[dn][r] *= alr[r];

    // P -> LDS: lane writes its q-row's k = n*16+lg*4..+3 as one b64 (cvt_pk packed)
    u16* Pw = (u16*)lP[wv] + lane16*PSTR;
    #pragma unroll
    for (int n = 0; n < 4; ++n){
      unsigned lo, hi;
      asm("v_cvt_pk_bf16_f32 %0, %1, %2" : "=v"(lo) : "v"(s[n][0]), "v"(s[n][1]));
      asm("v_cvt_pk_bf16_f32 %0, %1, %2" : "=v"(hi) : "v"(s[n][2]), "v"(s[n][3]));
      unsigned long long w = ((unsigned long long)hi << 32) | (unsigned long long)lo;
      *(unsigned long long*)(Pw + n*16 + lg*4) = w;
    }
    asm volatile("s_waitcnt lgkmcnt(0)" ::: "memory");

    // PV: A = P rows (q=lane16), B = Vt rows (d)
    const u16* Pr = (const u16*)lP[wv] + lane16*PSTR;
    short8 pa0 = *(const short8*)(Pr + lg*8);
    short8 pa1 = *(const short8*)(Pr + 32 + lg*8);
    __builtin_amdgcn_s_setprio(1);
    #pragma unroll
    for (int dn = 0; dn < 4; ++dn){
      int row = dn*16 + lane16;
      short8 bv0 = *(const short8*)(Vc + row*128 + (((lg    ) ^ (row&7))<<4));
      short8 bv1 = *(const short8*)(Vc + row*128 + (((4 + lg) ^ (row&7))<<4));
      o[dn] = mfma16(pa0, bv0, o[dn]);
      o[dn] = mfma16(pa1, bv1, o[dn]);
    }
    __builtin_amdgcn_s_setprio(0);

    __syncthreads();  // drains vmcnt (next tile ready) + protects buffer reuse
  }

  float inv = 1.f / lsum;
  float ivr[4];
  #pragma unroll
  for (int r = 0; r < 4; ++r) ivr[r] = __shfl(inv, (l & 48) | (lg*4 + r), 64);
  #pragma unroll
  for (int r = 0; r < 4; ++r){
    int t = q0 + wv*16 + lg*4 + r;
    #pragma unroll
    for (int dn = 0; dn < 4; ++dn)
      AO[((size_t)(b*T_ + t))*DM + h*64 + dn*16 + lane16] = f2b(o[dn][r]*ivr[r]);
  }
}

// ---------------- launch ----------------
extern "C" void kernel_launch(void* const* d_in, const int* in_sizes, int n_in,
                              void* d_out, int out_size, void* d_ws, size_t ws_size,
                              hipStream_t stream) {
  const float* x     = (const float*)d_in[0];
  const float* cosT  = (const float*)d_in[1];
  const float* sinT  = (const float*)d_in[2];
  const float* w_qkv = (const float*)d_in[3];
  const float* w_out = (const float*)d_in[4];
  float* out = (float*)d_out;

  char* ws = (char*)d_ws;
  u16* xb    = (u16*)(ws);                      // 16 MB   (8192x1024)
  u16* wqkvb = (u16*)(ws + 16777216);           // 6 MB    (3072x1024)
  u16* woutb = (u16*)(ws + 23068672);           // 2 MB    (1024x1024)
  u16* qkv   = (u16*)(ws + 25165824);           // 48 MB   (8192x3072)
  u16* Kh    = (u16*)(ws + 75497472);           // 16 MB
  u16* Vt    = (u16*)(ws + 92274688);           // 16 MB -> total 104 MB
  u16* Qh = xb;    // alias: x_bf16 dead after QKV GEMM
  u16* AO = qkv;   // alias: qkv dead after rope/reshape

  // 1) convert inputs to bf16
  k_f2b<<<4096, 256, 0, stream>>>(x,     xb,    BT_*DM/8);
  k_f2b<<<1536, 256, 0, stream>>>(w_qkv, wqkvb, F3*DM/8);
  k_f2b<<<512,  256, 0, stream>>>(w_out, woutb, DM*DM/8);

  // 2) qkv = x @ w_qkv^T   (8192x3072)
  k_gemm_bt<u16><<<(BT_/128)*(F3/128), 256, 0, stream>>>(xb, wqkvb, qkv, BT_, F3, DM);

  // 3) RoPE + head split + V transpose
  k_rope<<<dim3(T_/64, NH, B_), 256, 0, stream>>>(qkv, cosT, sinT, Qh, Kh, Vt);

  // 4) causal flash attention -> AO [B,T,DM] bf16
  k_attn<<<dim3(T_/64, B_*NH), 256, 0, stream>>>(Qh, Kh, Vt, AO);

  // 5) out = AO @ w_out^T  (f32 out)
  k_gemm_bt<float><<<(BT_/128)*(DM/128), 256, 0, stream>>>(AO, woutb, out, BT_, DM, DM);
}

// Round 4
// 194.717 us; speedup vs baseline: 2.0280x; 1.5223x over previous
//
#include <hip/hip_runtime.h>
#include <hip/hip_bf16.h>

// Problem constants
#define B_  4
#define T_  2048
#define DM  1024
#define NH  16
#define DH  64
#define BT_ (B_*T_)    // 8192
#define F3  (3*DM)     // 3072

typedef unsigned short u16;
typedef float  f32x4  __attribute__((ext_vector_type(4)));
typedef short  short8 __attribute__((ext_vector_type(8)));
typedef __bf16 bf16x8 __attribute__((ext_vector_type(8)));
typedef unsigned short u16x8 __attribute__((ext_vector_type(8)));

__device__ __forceinline__ u16 f2b(float f){
  __hip_bfloat16 h = __float2bfloat16(f);
  return *reinterpret_cast<u16*>(&h);
}
__device__ __forceinline__ float b2f(u16 u){
  __hip_bfloat16 h;
  *reinterpret_cast<u16*>(&h) = u;
  return __bfloat162float(h);
}

__device__ __forceinline__ f32x4 mfma16(short8 a, short8 b, f32x4 c){
  return __builtin_amdgcn_mfma_f32_16x16x32_bf16((bf16x8)a, (bf16x8)b, c, 0, 0, 0);
}

// async global->LDS, 16B per lane; lds dest must be wave-uniform base (+lane*16 implicit)
__device__ __forceinline__ void gll16(const void* g, void* l){
  __builtin_amdgcn_global_load_lds((const __attribute__((address_space(1))) unsigned int*)g,
                                   (__attribute__((address_space(3))) unsigned int*)l,
                                   16, 0, 0);
}

// ---------------- f32 -> bf16 convert (8 elems/thread) ----------------
__global__ __launch_bounds__(256) void k_f2b(const float* __restrict__ in,
                                             u16* __restrict__ out, int n8){
  int i = blockIdx.x*256 + threadIdx.x;
  if (i >= n8) return;
  const float4* p = reinterpret_cast<const float4*>(in) + (size_t)i*2;
  float4 a = p[0], b = p[1];
  u16x8 r;
  r[0]=f2b(a.x); r[1]=f2b(a.y); r[2]=f2b(a.z); r[3]=f2b(a.w);
  r[4]=f2b(b.x); r[5]=f2b(b.y); r[6]=f2b(b.z); r[7]=f2b(b.w);
  *(reinterpret_cast<u16x8*>(out) + i) = r;
}

// ---------------- GEMM C = A * B^T  (A: MxK bf16, B: NxK bf16) ----------------
template<typename OUT>
__global__ __launch_bounds__(256, 2) void k_gemm_bt(const u16* __restrict__ A,
                                                    const u16* __restrict__ Bm,
                                                    OUT* __restrict__ C,
                                                    int M, int N, int K){
  __shared__ __attribute__((aligned(16))) u16 lA[128*64];
  __shared__ __attribute__((aligned(16))) u16 lB[128*64];

  int nbn = N >> 7;
  int nwg = gridDim.x;
  int bid = blockIdx.x;
  int wg = bid;
  if ((nwg & 7) == 0) { int q = nwg >> 3; wg = (bid & 7)*q + (bid >> 3); } // XCD swizzle
  int bm = wg / nbn, bn = wg % nbn;

  int tid = threadIdx.x, wv = tid >> 6, l = tid & 63;
  int lane16 = l & 15, lg = l >> 4;
  int wr = wv >> 1, wc = wv & 1;

  f32x4 acc[4][4] = {};

  const u16* pA = A + (size_t)(bm*128 + wv*8 + (l>>3))*K + (l&7)*8;
  const u16* pB = Bm + (size_t)(bn*128 + wv*8 + (l>>3))*K + (l&7)*8;
  char* lAb = (char*)lA + wv*1024;
  char* lBb = (char*)lB + wv*1024;

  int nk = K >> 6;
  for (int kt = 0; kt < nk; ++kt){
    const u16* gA = pA + kt*64;
    const u16* gB = pB + kt*64;
    #pragma unroll
    for (int c = 0; c < 4; ++c){
      gll16(gA + (size_t)c*32*K, lAb + c*4096);
      gll16(gB + (size_t)c*32*K, lBb + c*4096);
    }
    __syncthreads();
    #pragma unroll
    for (int kk = 0; kk < 2; ++kk){
      short8 am[4], bb[4];
      #pragma unroll
      for (int m = 0; m < 4; ++m)
        am[m] = *(const short8*)&lA[(wr*64 + m*16 + lane16)*64 + kk*32 + lg*8];
      #pragma unroll
      for (int n = 0; n < 4; ++n)
        bb[n] = *(const short8*)&lB[(wc*64 + n*16 + lane16)*64 + kk*32 + lg*8];
      #pragma unroll
      for (int m = 0; m < 4; ++m)
        #pragma unroll
        for (int n = 0; n < 4; ++n)
          acc[m][n] = mfma16(am[m], bb[n], acc[m][n]);
    }
    __syncthreads();
  }

  #pragma unroll
  for (int m = 0; m < 4; ++m){
    #pragma unroll
    for (int n = 0; n < 4; ++n){
      #pragma unroll
      for (int r = 0; r < 4; ++r){
        int grow = bm*128 + wr*64 + m*16 + lg*4 + r;
        int gcol = bn*128 + wc*64 + n*16 + lane16;
        float v = acc[m][n][r];
        if constexpr (sizeof(OUT) == 2) C[(size_t)grow*N + gcol] = (OUT)f2b(v);
        else                            C[(size_t)grow*N + gcol] = v;
      }
    }
  }
}

// ---------------- RoPE + head-split + V transpose ----------------
__global__ __launch_bounds__(256) void k_rope(const u16* __restrict__ qkv,
    const float* __restrict__ cosT, const float* __restrict__ sinT,
    u16* __restrict__ Qh, u16* __restrict__ Kh, u16* __restrict__ Vt){
  __shared__ float lsV[64][65];
  int t0 = blockIdx.x*64, h = blockIdx.y, b = blockIdx.z;
  int bh = b*NH + h;
  int i = threadIdx.x;
  int tl = i >> 2, dc = i & 3;
  int t = t0 + tl;
  size_t rowbase = (size_t)(b*T_ + t)*F3;
  int d0 = dc*8;

  float c1[8], s1[8], c2[8], s2[8];
  const float* cp = cosT + t*64 + d0;
  const float* sp = sinT + t*64 + d0;
  #pragma unroll
  for (int j=0;j<8;++j){ c1[j]=cp[j]; s1[j]=sp[j]; c2[j]=cp[32+j]; s2[j]=sp[32+j]; }

  #pragma unroll
  for (int qk = 0; qk < 2; ++qk){
    u16x8 u1 = *(const u16x8*)(qkv + rowbase + qk*DM + h*64 + d0);
    u16x8 u2 = *(const u16x8*)(qkv + rowbase + qk*DM + h*64 + d0 + 32);
    u16x8 o1, o2;
    float sc = (qk == 0) ? 0.125f : 1.0f;   // fold 1/sqrt(64) into Q
    #pragma unroll
    for (int j=0;j<8;++j){
      float a = b2f(u1[j]), bb = b2f(u2[j]);
      o1[j] = f2b((a*c1[j] - bb*s1[j])*sc);
      o2[j] = f2b((bb*c2[j] + a*s2[j])*sc);
    }
    u16* dst = (qk==0 ? Qh : Kh) + ((size_t)bh*T_ + t)*64 + d0;
    *(u16x8*)dst = o1;
    *(u16x8*)(dst + 32) = o2;
  }

  // V: load [t][d] tile, transpose through LDS, store [d][t]
  #pragma unroll
  for (int half = 0; half < 2; ++half){
    u16x8 v = *(const u16x8*)(qkv + rowbase + 2*DM + h*64 + dc*16 + half*8);
    #pragma unroll
    for (int j=0;j<8;++j) lsV[tl][dc*16 + half*8 + j] = b2f(v[j]);
  }
  __syncthreads();
  int dl = i >> 2, tc = i & 3;
  u16x8 w0, w1;
  #pragma unroll
  for (int j=0;j<8;++j){ w0[j] = f2b(lsV[tc*16+j][dl]); w1[j] = f2b(lsV[tc*16+8+j][dl]); }
  u16* vd = Vt + ((size_t)bh*64 + dl)*T_ + t0 + tc*16;
  *(u16x8*)vd = w0;
  *(u16x8*)(vd+8) = w1;
}

// ---------------- causal flash attention ----------------
// 3-deep LDS pipeline with counted vmcnt + raw barrier; in-register P via
// cvt_pk + permlane swaps (distinct-value operands only!); defer-max;
// XCD-locality grid decode. Softmax reductions via __shfl_xor (proven; the
// permlane reduction variant coalesced its two same-value asm operands into
// ONE register -> swap-with-self -> garbage. Do not reintroduce without
// forced-distinct registers.)
__global__ __launch_bounds__(256, 2) void k_attn(const u16* __restrict__ Qh,
    const u16* __restrict__ Kh, const u16* __restrict__ Vt, u16* __restrict__ AO){
  __shared__ __attribute__((aligned(16))) u16 lK[3][64*64];
  __shared__ __attribute__((aligned(16))) u16 lV[3][64*64];

  // bid bits: [2:0]=bh_lo (XCD), [5:3]=bh_hi, [10:6]=31-qt  -> all q-blocks of a
  // bh land on one XCD; big qt dispatched first.
  int bid = (int)blockIdx.x;
  int qt = 31 - (bid >> 6);
  int bh = ((bid >> 3) & 7) * 8 + (bid & 7);
  int q0 = qt*64;
  int b = bh >> 4, h = bh & 15;
  int tid = threadIdx.x, wv = tid >> 6, l = tid & 63;
  int lane16 = l & 15, lg = l >> 4;

  // Q fragments (B-operand of swapped QK^T)
  short8 bq[2];
  const u16* qp = Qh + ((size_t)bh*T_ + q0 + wv*16 + lane16)*64 + lg*8;
  bq[0] = *(const short8*)qp;
  bq[1] = *(const short8*)(qp + 32);

  f32x4 o[4] = {};                       // o[dn][r]: q_local=lg*4+r, d=dn*16+lane16
  float mrow = -INFINITY, lsum = 0.f;    // softmax state for q = q0+wv*16+lane16

  const u16* Kb = Kh + (size_t)bh*T_*64;
  const u16* Vb = Vt + (size_t)bh*64*T_;

  int rl = l >> 3;                 // row within 8-row staging group
  int sc = ((l&7) ^ rl) * 8;       // pre-swizzled source column (elements)
  int nt = qt + 1;

  // stage: 4 gll16 per wave (K c0, V c0, K c1, V c1)
  auto STAGE = [&](int tile, int bufi){
    char* kd = (char*)lK[bufi] + wv*1024;
    char* vd = (char*)lV[bufi] + wv*1024;
    const u16* kg = Kb + (size_t)(tile*64 + wv*8 + rl)*64 + sc;
    const u16* vg = Vb + (size_t)(wv*8 + rl)*T_ + tile*64 + sc;
    gll16(kg, kd);
    gll16(vg, vd);
    gll16(kg + 32*64, kd + 4096);
    gll16(vg + (size_t)32*T_, vd + 4096);
  };

  STAGE(0, 0);
  if (nt > 1) STAGE(1, 1);

  int bc = 0;  // buffer holding current tile
  for (int it = 0; it < nt; ++it){
    // own loads for tile `it` are all older than the newest 4 (tile it+1's)
    if (it + 1 < nt) asm volatile("s_waitcnt vmcnt(4)" ::: "memory");
    else             asm volatile("s_waitcnt vmcnt(0)" ::: "memory");
    asm volatile("s_barrier" ::: "memory");

    int b2 = bc + 2; if (b2 >= 3) b2 -= 3;
    if (it + 2 < nt) STAGE(it + 2, b2);   // overwrites buffer of tile it-1 (safe: post-barrier)

    const char* Kc = (const char*)lK[bc];
    const char* Vc = (const char*)lV[bc];
    int kv0 = it*64;

    // S^T tile: s[n][r] = S[k = kv0+n*16+lg*4+r][q = lane16-row of this wave]
    f32x4 s[4];
    __builtin_amdgcn_s_setprio(1);
    #pragma unroll
    for (int n = 0; n < 4; ++n){
      int row = n*16 + lane16;
      short8 ak0 = *(const short8*)(Kc + row*128 + (((lg    ) ^ (row&7))<<4));
      short8 ak1 = *(const short8*)(Kc + row*128 + (((4 + lg) ^ (row&7))<<4));
      f32x4 z = {};
      z = mfma16(ak0, bq[0], z);
      z = mfma16(ak1, bq[1], z);
      s[n] = z;
    }
    __builtin_amdgcn_s_setprio(0);

    if (it == nt-1){  // only diagonal tile needs masking
      int q_abs = q0 + wv*16 + lane16;
      #pragma unroll
      for (int n = 0; n < 4; ++n)
        #pragma unroll
        for (int r = 0; r < 4; ++r){
          int key = kv0 + n*16 + lg*4 + r;
          if (key > q_abs) s[n][r] = -1e30f;
        }
    }

    // per-q max (q = lane16; 16 values per lane, row spread over lanes ^16,^32)
    float pm = s[0][0];
    #pragma unroll
    for (int n = 0; n < 4; ++n)
      #pragma unroll
      for (int r = 0; r < 4; ++r) pm = fmaxf(pm, s[n][r]);
    pm = fmaxf(pm, __shfl_xor(pm, 16, 64));
    pm = fmaxf(pm, __shfl_xor(pm, 32, 64));

    // defer-max: rescale only when max grew by > 8
    if (__any(pm > mrow + 8.f)){
      float mn = fmaxf(mrow, pm);
      float al = __expf(mrow - mn);
      mrow = mn;
      float alr[4];
      #pragma unroll
      for (int r = 0; r < 4; ++r) alr[r] = __shfl(al, (l & 48) | (lg*4 + r), 64);
      #pragma unroll
      for (int dn = 0; dn < 4; ++dn)
        #pragma unroll
        for (int r = 0; r < 4; ++r) o[dn][r] *= alr[r];
      lsum *= al;
    }

    float rs = 0.f;
    #pragma unroll
    for (int n = 0; n < 4; ++n)
      #pragma unroll
      for (int r = 0; r < 4; ++r){ float p = __expf(s[n][r] - mrow); s[n][r] = p; rs += p; }
    rs += __shfl_xor(rs, 16, 64);
    rs += __shfl_xor(rs, 32, 64);
    lsum += rs;

    // pack P to bf16 in-register: d[n][h] covers k = n*16 + lg*4 + 2h + {0,1}
    unsigned d[4][2];
    #pragma unroll
    for (int n = 0; n < 4; ++n){
      asm("v_cvt_pk_bf16_f32 %0, %1, %2" : "=v"(d[n][0]) : "v"(s[n][0]), "v"(s[n][1]));
      asm("v_cvt_pk_bf16_f32 %0, %1, %2" : "=v"(d[n][1]) : "v"(s[n][2]), "v"(s[n][3]));
    }
    // permute into A-fragment layout: lane (lg) holds P[q=lane16][k=lg*8..+8] (+32 for pa1)
    // pair (d[2g][h], d[2g+1][h]) --swap32--> --swap16--> {slot h, slot 2+h} of pa_g
    // (operands hold DIFFERENT values -> regalloc cannot coalesce them)
    union { unsigned u[4]; short8 v; } pk0, pk1;
    #pragma unroll
    for (int g = 0; g < 2; ++g){
      #pragma unroll
      for (int hh = 0; hh < 2; ++hh){
        unsigned A = d[2*g][hh], Bv = d[2*g+1][hh];
        asm("v_permlane32_swap_b32 %0, %1" : "+v"(A), "+v"(Bv));
        asm("v_permlane16_swap_b32 %0, %1" : "+v"(A), "+v"(Bv));
        if (g == 0){ pk0.u[hh] = A; pk0.u[2+hh] = Bv; }
        else       { pk1.u[hh] = A; pk1.u[2+hh] = Bv; }
      }
    }

    // PV: A = P rows (q=lane16), B = Vt rows (d)
    __builtin_amdgcn_s_setprio(1);
    #pragma unroll
    for (int dn = 0; dn < 4; ++dn){
      int row = dn*16 + lane16;
      short8 bv0 = *(const short8*)(Vc + row*128 + (((lg    ) ^ (row&7))<<4));
      short8 bv1 = *(const short8*)(Vc + row*128 + (((4 + lg) ^ (row&7))<<4));
      o[dn] = mfma16(pk0.v, bv0, o[dn]);
      o[dn] = mfma16(pk1.v, bv1, o[dn]);
    }
    __builtin_amdgcn_s_setprio(0);

    bc = (bc + 1 == 3) ? 0 : bc + 1;
  }

  float inv = 1.f / lsum;
  float ivr[4];
  #pragma unroll
  for (int r = 0; r < 4; ++r) ivr[r] = __shfl(inv, (l & 48) | (lg*4 + r), 64);
  #pragma unroll
  for (int r = 0; r < 4; ++r){
    int t = q0 + wv*16 + lg*4 + r;
    #pragma unroll
    for (int dn = 0; dn < 4; ++dn)
      AO[((size_t)(b*T_ + t))*DM + h*64 + dn*16 + lane16] = f2b(o[dn][r]*ivr[r]);
  }
}

// ---------------- launch ----------------
extern "C" void kernel_launch(void* const* d_in, const int* in_sizes, int n_in,
                              void* d_out, int out_size, void* d_ws, size_t ws_size,
                              hipStream_t stream) {
  const float* x     = (const float*)d_in[0];
  const float* cosT  = (const float*)d_in[1];
  const float* sinT  = (const float*)d_in[2];
  const float* w_qkv = (const float*)d_in[3];
  const float* w_out = (const float*)d_in[4];
  float* out = (float*)d_out;

  char* ws = (char*)d_ws;
  u16* xb    = (u16*)(ws);                      // 16 MB   (8192x1024)
  u16* wqkvb = (u16*)(ws + 16777216);           // 6 MB    (3072x1024)
  u16* woutb = (u16*)(ws + 23068672);           // 2 MB    (1024x1024)
  u16* qkv   = (u16*)(ws + 25165824);           // 48 MB   (8192x3072)
  u16* Kh    = (u16*)(ws + 75497472);           // 16 MB
  u16* Vt    = (u16*)(ws + 92274688);           // 16 MB -> total 104 MB
  u16* Qh = xb;    // alias: x_bf16 dead after QKV GEMM
  u16* AO = qkv;   // alias: qkv dead after rope/reshape

  // 1) convert inputs to bf16
  k_f2b<<<4096, 256, 0, stream>>>(x,     xb,    BT_*DM/8);
  k_f2b<<<1536, 256, 0, stream>>>(w_qkv, wqkvb, F3*DM/8);
  k_f2b<<<512,  256, 0, stream>>>(w_out, woutb, DM*DM/8);

  // 2) qkv = x @ w_qkv^T   (8192x3072)
  k_gemm_bt<u16><<<(BT_/128)*(F3/128), 256, 0, stream>>>(xb, wqkvb, qkv, BT_, F3, DM);

  // 3) RoPE + head split + V transpose
  k_rope<<<dim3(T_/64, NH, B_), 256, 0, stream>>>(qkv, cosT, sinT, Qh, Kh, Vt);

  // 4) causal flash attention -> AO [B,T,DM] bf16
  k_attn<<<2048, 256, 0, stream>>>(Qh, Kh, Vt, AO);

  // 5) out = AO @ w_out^T  (f32 out)
  k_gemm_bt<float><<<(BT_/128)*(DM/128), 256, 0, stream>>>(AO, woutb, out, BT_, DM, DM);
}

// Round 5
// 179.391 us; speedup vs baseline: 2.2013x; 1.0854x over previous
//
#include <hip/hip_runtime.h>
#include <hip/hip_bf16.h>

// Problem constants
#define B_  4
#define T_  2048
#define DM  1024
#define NH  16
#define DH  64
#define BT_ (B_*T_)    // 8192
#define F3  (3*DM)     // 3072

typedef unsigned short u16;
typedef float  f32x4  __attribute__((ext_vector_type(4)));
typedef short  short8 __attribute__((ext_vector_type(8)));
typedef __bf16 bf16x8 __attribute__((ext_vector_type(8)));
typedef unsigned short u16x8 __attribute__((ext_vector_type(8)));

__device__ __forceinline__ u16 f2b(float f){
  __hip_bfloat16 h = __float2bfloat16(f);
  return *reinterpret_cast<u16*>(&h);
}
__device__ __forceinline__ float b2f(u16 u){
  __hip_bfloat16 h;
  *reinterpret_cast<u16*>(&h) = u;
  return __bfloat162float(h);
}

__device__ __forceinline__ f32x4 mfma16(short8 a, short8 b, f32x4 c){
  return __builtin_amdgcn_mfma_f32_16x16x32_bf16((bf16x8)a, (bf16x8)b, c, 0, 0, 0);
}

// async global->LDS, 16B per lane; lds dest must be wave-uniform base (+lane*16 implicit)
__device__ __forceinline__ void gll16(const void* g, void* l){
  __builtin_amdgcn_global_load_lds((const __attribute__((address_space(1))) unsigned int*)g,
                                   (__attribute__((address_space(3))) unsigned int*)l,
                                   16, 0, 0);
}

// ---------------- f32 -> bf16 convert (8 elems/thread) ----------------
__global__ __launch_bounds__(256) void k_f2b(const float* __restrict__ in,
                                             u16* __restrict__ out, int n8){
  int i = blockIdx.x*256 + threadIdx.x;
  if (i >= n8) return;
  const float4* p = reinterpret_cast<const float4*>(in) + (size_t)i*2;
  float4 a = p[0], b = p[1];
  u16x8 r;
  r[0]=f2b(a.x); r[1]=f2b(a.y); r[2]=f2b(a.z); r[3]=f2b(a.w);
  r[4]=f2b(b.x); r[5]=f2b(b.y); r[6]=f2b(b.z); r[7]=f2b(b.w);
  *(reinterpret_cast<u16x8*>(out) + i) = r;
}

// ---------------- generic GEMM C = A * B^T (for the output projection) ----------------
template<typename OUT>
__global__ __launch_bounds__(256, 2) void k_gemm_bt(const u16* __restrict__ A,
                                                    const u16* __restrict__ Bm,
                                                    OUT* __restrict__ C,
                                                    int M, int N, int K){
  __shared__ __attribute__((aligned(16))) u16 lA[128*64];
  __shared__ __attribute__((aligned(16))) u16 lB[128*64];

  int nbn = N >> 7;
  int nwg = gridDim.x;
  int bid = blockIdx.x;
  int wg = bid;
  if ((nwg & 7) == 0) { int q = nwg >> 3; wg = (bid & 7)*q + (bid >> 3); } // XCD swizzle
  int bm = wg / nbn, bn = wg % nbn;

  int tid = threadIdx.x, wv = tid >> 6, l = tid & 63;
  int lane16 = l & 15, lg = l >> 4;
  int wr = wv >> 1, wc = wv & 1;

  f32x4 acc[4][4] = {};

  const u16* pA = A + (size_t)(bm*128 + wv*8 + (l>>3))*K + (l&7)*8;
  const u16* pB = Bm + (size_t)(bn*128 + wv*8 + (l>>3))*K + (l&7)*8;
  char* lAb = (char*)lA + wv*1024;
  char* lBb = (char*)lB + wv*1024;

  int nk = K >> 6;
  for (int kt = 0; kt < nk; ++kt){
    const u16* gA = pA + kt*64;
    const u16* gB = pB + kt*64;
    #pragma unroll
    for (int c = 0; c < 4; ++c){
      gll16(gA + (size_t)c*32*K, lAb + c*4096);
      gll16(gB + (size_t)c*32*K, lBb + c*4096);
    }
    __syncthreads();
    #pragma unroll
    for (int kk = 0; kk < 2; ++kk){
      short8 am[4], bb[4];
      #pragma unroll
      for (int m = 0; m < 4; ++m)
        am[m] = *(const short8*)&lA[(wr*64 + m*16 + lane16)*64 + kk*32 + lg*8];
      #pragma unroll
      for (int n = 0; n < 4; ++n)
        bb[n] = *(const short8*)&lB[(wc*64 + n*16 + lane16)*64 + kk*32 + lg*8];
      #pragma unroll
      for (int m = 0; m < 4; ++m)
        #pragma unroll
        for (int n = 0; n < 4; ++n)
          acc[m][n] = mfma16(am[m], bb[n], acc[m][n]);
    }
    __syncthreads();
  }

  #pragma unroll
  for (int m = 0; m < 4; ++m){
    #pragma unroll
    for (int n = 0; n < 4; ++n){
      #pragma unroll
      for (int r = 0; r < 4; ++r){
        int grow = bm*128 + wr*64 + m*16 + lg*4 + r;
        int gcol = bn*128 + wc*64 + n*16 + lane16;
        float v = acc[m][n][r];
        if constexpr (sizeof(OUT) == 2) C[(size_t)grow*N + gcol] = (OUT)f2b(v);
        else                            C[(size_t)grow*N + gcol] = v;
      }
    }
  }
}

// ---------------- QKV GEMM with fused RoPE + head-split + V-transpose epilogue ----
// qkv = x @ w_qkv^T, tiles 128x128. Each wave's 64-col span is exactly one head,
// and the RoPE pair (d, d+32) is (acc n, acc n+2) in the SAME lane. cos/sin tables
// satisfy cos[t][d+32]==cos[t][d], so 2 cos + 2 sin loads per (m,r).
// Q is pre-scaled by (1/8)*log2(e) (attn softmax uses exp2).
// V tiles are transposed through the (idle) staging LDS and stored [bh][d][t].
__global__ __launch_bounds__(256, 2) void k_gemm_qkv(const u16* __restrict__ A,
    const u16* __restrict__ Bm,
    const float* __restrict__ cosT, const float* __restrict__ sinT,
    u16* __restrict__ Qh, u16* __restrict__ Kh, u16* __restrict__ Vt){
  __shared__ __attribute__((aligned(16))) u16 lsmem[2*128*64];  // 32 KB
  u16* lA = lsmem;
  u16* lB = lsmem + 128*64;
  const int K = DM;
  const int nbn = F3 >> 7;   // 24

  int bid = blockIdx.x;
  int q8 = (64*24) >> 3;
  int wg = (bid & 7)*q8 + (bid >> 3);   // XCD swizzle (1536 % 8 == 0)
  int bm = wg / nbn, bn = wg % nbn;

  int tid = threadIdx.x, wv = tid >> 6, l = tid & 63;
  int lane16 = l & 15, lg = l >> 4;
  int wr = wv >> 1, wc = wv & 1;

  f32x4 acc[4][4] = {};

  const u16* pA = A + (size_t)(bm*128 + wv*8 + (l>>3))*K + (l&7)*8;
  const u16* pB = Bm + (size_t)(bn*128 + wv*8 + (l>>3))*K + (l&7)*8;
  char* lAb = (char*)lA + wv*1024;
  char* lBb = (char*)lB + wv*1024;

  int nk = K >> 6;
  for (int kt = 0; kt < nk; ++kt){
    const u16* gA = pA + kt*64;
    const u16* gB = pB + kt*64;
    #pragma unroll
    for (int c = 0; c < 4; ++c){
      gll16(gA + (size_t)c*32*K, lAb + c*4096);
      gll16(gB + (size_t)c*32*K, lBb + c*4096);
    }
    __syncthreads();
    #pragma unroll
    for (int kk = 0; kk < 2; ++kk){
      short8 am[4], bb[4];
      #pragma unroll
      for (int m = 0; m < 4; ++m)
        am[m] = *(const short8*)&lA[(wr*64 + m*16 + lane16)*64 + kk*32 + lg*8];
      #pragma unroll
      for (int n = 0; n < 4; ++n)
        bb[n] = *(const short8*)&lB[(wc*64 + n*16 + lane16)*64 + kk*32 + lg*8];
      #pragma unroll
      for (int m = 0; m < 4; ++m)
        #pragma unroll
        for (int n = 0; n < 4; ++n)
          acc[m][n] = mfma16(am[m], bb[n], acc[m][n]);
    }
    __syncthreads();
  }

  int sect = bn >> 3;          // 0=q, 1=k, 2=v (section boundaries are 128-aligned)
  int t0 = bm*128;
  int b  = t0 >> 11;           // batch (2048 is a multiple of 128)
  int tt0 = t0 & 2047;         // sequence offset within batch

  if (sect < 2){
    u16* dst = sect ? Kh : Qh;
    float scq = sect ? 1.0f : 0.18033688011f;   // (1/8)*log2(e) folded into Q
    int fcol = (bn & 7)*128 + wc*64;            // feature within section, 64-aligned
    int h = fcol >> 6;                          // whole wave in one head
    size_t hrow = (size_t)(b*NH + h)*T_;
    #pragma unroll
    for (int m = 0; m < 4; ++m){
      #pragma unroll
      for (int r = 0; r < 4; ++r){
        int t = tt0 + wr*64 + m*16 + lg*4 + r;
        const float* cp = cosT + (size_t)t*64;
        const float* sp = sinT + (size_t)t*64;
        float c0 = cp[lane16],      s0 = sp[lane16];
        float c1 = cp[16 + lane16], s1 = sp[16 + lane16];
        float a0 = acc[m][0][r], a1 = acc[m][1][r];
        float a2 = acc[m][2][r], a3 = acc[m][3][r];
        size_t base = (hrow + t)*64;
        dst[base + lane16]      = f2b((a0*c0 - a2*s0)*scq);   // d = lane16
        dst[base + 16 + lane16] = f2b((a1*c1 - a3*s1)*scq);   // d = 16+lane16
        dst[base + 32 + lane16] = f2b((a2*c0 + a0*s0)*scq);   // d = 32+lane16
        dst[base + 48 + lane16] = f2b((a3*c1 + a1*s1)*scq);   // d = 48+lane16
      }
    }
  } else {
    // V: transpose 128t x 128f tile -> Vt[bh][d][t], via LDS in two 64-col passes
    int fbase = (bn & 7)*128;
    for (int cc = 0; cc < 2; ++cc){
      __syncthreads();
      if (wc == cc){
        #pragma unroll
        for (int m = 0; m < 4; ++m)
          #pragma unroll
          for (int n = 0; n < 4; ++n)
            #pragma unroll
            for (int r = 0; r < 4; ++r){
              int cl = n*16 + lane16;              // 0..63 (d within head)
              int tl = wr*64 + m*16 + lg*4 + r;    // 0..127
              lsmem[cl*136 + tl] = f2b(acc[m][n][r]);
            }
      }
      __syncthreads();
      int h = (fbase + cc*64) >> 6;
      int dl = tid >> 2, seg = tid & 3;
      const u16* src = lsmem + dl*136 + seg*32;
      u16* dp = Vt + ((size_t)(b*NH + h)*64 + dl)*T_ + tt0 + seg*32;
      *(u16x8*)dp      = *(const u16x8*)src;
      *(u16x8*)(dp+8)  = *(const u16x8*)(src+8);
      *(u16x8*)(dp+16) = *(const u16x8*)(src+16);
      *(u16x8*)(dp+24) = *(const u16x8*)(src+24);
    }
  }
}

// ---------------- causal flash attention ----------------
// 3-deep LDS pipeline with counted vmcnt + raw barrier; in-register P via
// cvt_pk + permlane swaps (distinct-value operands only!); defer-max;
// XCD-locality grid decode. Scores arrive pre-scaled by log2(e)/8 -> exp2 softmax.
// Softmax reductions via __shfl_xor (permlane reduction variant coalesced its two
// same-value asm operands into ONE register -> swap-with-self -> garbage).
__global__ __launch_bounds__(256, 2) void k_attn(const u16* __restrict__ Qh,
    const u16* __restrict__ Kh, const u16* __restrict__ Vt, u16* __restrict__ AO){
  __shared__ __attribute__((aligned(16))) u16 lK[3][64*64];
  __shared__ __attribute__((aligned(16))) u16 lV[3][64*64];

  // bid bits: [2:0]=bh_lo (XCD), [5:3]=bh_hi, [10:6]=31-qt  -> all q-blocks of a
  // bh land on one XCD; big qt dispatched first.
  int bid = (int)blockIdx.x;
  int qt = 31 - (bid >> 6);
  int bh = ((bid >> 3) & 7) * 8 + (bid & 7);
  int q0 = qt*64;
  int b = bh >> 4, h = bh & 15;
  int tid = threadIdx.x, wv = tid >> 6, l = tid & 63;
  int lane16 = l & 15, lg = l >> 4;

  // Q fragments (B-operand of swapped QK^T)
  short8 bq[2];
  const u16* qp = Qh + ((size_t)bh*T_ + q0 + wv*16 + lane16)*64 + lg*8;
  bq[0] = *(const short8*)qp;
  bq[1] = *(const short8*)(qp + 32);

  f32x4 o[4] = {};                       // o[dn][r]: q_local=lg*4+r, d=dn*16+lane16
  float mrow = -INFINITY, lsum = 0.f;    // softmax state for q = q0+wv*16+lane16

  const u16* Kb = Kh + (size_t)bh*T_*64;
  const u16* Vb = Vt + (size_t)bh*64*T_;

  int rl = l >> 3;                 // row within 8-row staging group
  int sc = ((l&7) ^ rl) * 8;       // pre-swizzled source column (elements)
  int nt = qt + 1;

  // stage: 4 gll16 per wave (K c0, V c0, K c1, V c1)
  auto STAGE = [&](int tile, int bufi){
    char* kd = (char*)lK[bufi] + wv*1024;
    char* vd = (char*)lV[bufi] + wv*1024;
    const u16* kg = Kb + (size_t)(tile*64 + wv*8 + rl)*64 + sc;
    const u16* vg = Vb + (size_t)(wv*8 + rl)*T_ + tile*64 + sc;
    gll16(kg, kd);
    gll16(vg, vd);
    gll16(kg + 32*64, kd + 4096);
    gll16(vg + (size_t)32*T_, vd + 4096);
  };

  STAGE(0, 0);
  if (nt > 1) STAGE(1, 1);

  int bc = 0;  // buffer holding current tile
  for (int it = 0; it < nt; ++it){
    // own loads for tile `it` are all older than the newest 4 (tile it+1's)
    if (it + 1 < nt) asm volatile("s_waitcnt vmcnt(4)" ::: "memory");
    else             asm volatile("s_waitcnt vmcnt(0)" ::: "memory");
    asm volatile("s_barrier" ::: "memory");

    int b2 = bc + 2; if (b2 >= 3) b2 -= 3;
    if (it + 2 < nt) STAGE(it + 2, b2);   // overwrites buffer of tile it-1 (safe: post-barrier)

    const char* Kc = (const char*)lK[bc];
    const char* Vc = (const char*)lV[bc];
    int kv0 = it*64;

    // S^T tile: s[n][r] = S[k = kv0+n*16+lg*4+r][q = lane16-row of this wave]
    f32x4 s[4];
    __builtin_amdgcn_s_setprio(1);
    #pragma unroll
    for (int n = 0; n < 4; ++n){
      int row = n*16 + lane16;
      short8 ak0 = *(const short8*)(Kc + row*128 + (((lg    ) ^ (row&7))<<4));
      short8 ak1 = *(const short8*)(Kc + row*128 + (((4 + lg) ^ (row&7))<<4));
      f32x4 z = {};
      z = mfma16(ak0, bq[0], z);
      z = mfma16(ak1, bq[1], z);
      s[n] = z;
    }
    __builtin_amdgcn_s_setprio(0);

    if (it == nt-1){  // only diagonal tile needs masking
      int q_abs = q0 + wv*16 + lane16;
      #pragma unroll
      for (int n = 0; n < 4; ++n)
        #pragma unroll
        for (int r = 0; r < 4; ++r){
          int key = kv0 + n*16 + lg*4 + r;
          if (key > q_abs) s[n][r] = -1e30f;
        }
    }

    // per-q max (q = lane16; 16 values per lane, row spread over lanes ^16,^32)
    float pm = s[0][0];
    #pragma unroll
    for (int n = 0; n < 4; ++n)
      #pragma unroll
      for (int r = 0; r < 4; ++r) pm = fmaxf(pm, s[n][r]);
    pm = fmaxf(pm, __shfl_xor(pm, 16, 64));
    pm = fmaxf(pm, __shfl_xor(pm, 32, 64));

    // defer-max: rescale only when max grew by > 8 (log2 units; P bounded by 2^8)
    if (__any(pm > mrow + 8.f)){
      float mn = fmaxf(mrow, pm);
      float al = __builtin_amdgcn_exp2f(mrow - mn);
      mrow = mn;
      float alr[4];
      #pragma unroll
      for (int r = 0; r < 4; ++r) alr[r] = __shfl(al, (l & 48) | (lg*4 + r), 64);
      #pragma unroll
      for (int dn = 0; dn < 4; ++dn)
        #pragma unroll
        for (int r = 0; r < 4; ++r) o[dn][r] *= alr[r];
      lsum *= al;
    }

    float rs = 0.f;
    #pragma unroll
    for (int n = 0; n < 4; ++n)
      #pragma unroll
      for (int r = 0; r < 4; ++r){
        float p = __builtin_amdgcn_exp2f(s[n][r] - mrow);
        s[n][r] = p; rs += p;
      }
    rs += __shfl_xor(rs, 16, 64);
    rs += __shfl_xor(rs, 32, 64);
    lsum += rs;

    // pack P to bf16 in-register: d[n][h] covers k = n*16 + lg*4 + 2h + {0,1}
    unsigned d[4][2];
    #pragma unroll
    for (int n = 0; n < 4; ++n){
      asm("v_cvt_pk_bf16_f32 %0, %1, %2" : "=v"(d[n][0]) : "v"(s[n][0]), "v"(s[n][1]));
      asm("v_cvt_pk_bf16_f32 %0, %1, %2" : "=v"(d[n][1]) : "v"(s[n][2]), "v"(s[n][3]));
    }
    // permute into A-fragment layout: lane (lg) holds P[q=lane16][k=lg*8..+8] (+32 for pa1)
    // pair (d[2g][h], d[2g+1][h]) --swap32--> --swap16--> {slot h, slot 2+h} of pa_g
    // (operands hold DIFFERENT values -> regalloc cannot coalesce them)
    union { unsigned u[4]; short8 v; } pk0, pk1;
    #pragma unroll
    for (int g = 0; g < 2; ++g){
      #pragma unroll
      for (int hh = 0; hh < 2; ++hh){
        unsigned A = d[2*g][hh], Bv = d[2*g+1][hh];
        asm("v_permlane32_swap_b32 %0, %1" : "+v"(A), "+v"(Bv));
        asm("v_permlane16_swap_b32 %0, %1" : "+v"(A), "+v"(Bv));
        if (g == 0){ pk0.u[hh] = A; pk0.u[2+hh] = Bv; }
        else       { pk1.u[hh] = A; pk1.u[2+hh] = Bv; }
      }
    }

    // PV: A = P rows (q=lane16), B = Vt rows (d)
    __builtin_amdgcn_s_setprio(1);
    #pragma unroll
    for (int dn = 0; dn < 4; ++dn){
      int row = dn*16 + lane16;
      short8 bv0 = *(const short8*)(Vc + row*128 + (((lg    ) ^ (row&7))<<4));
      short8 bv1 = *(const short8*)(Vc + row*128 + (((4 + lg) ^ (row&7))<<4));
      o[dn] = mfma16(pk0.v, bv0, o[dn]);
      o[dn] = mfma16(pk1.v, bv1, o[dn]);
    }
    __builtin_amdgcn_s_setprio(0);

    bc = (bc + 1 == 3) ? 0 : bc + 1;
  }

  float inv = 1.f / lsum;
  float ivr[4];
  #pragma unroll
  for (int r = 0; r < 4; ++r) ivr[r] = __shfl(inv, (l & 48) | (lg*4 + r), 64);
  #pragma unroll
  for (int r = 0; r < 4; ++r){
    int t = q0 + wv*16 + lg*4 + r;
    #pragma unroll
    for (int dn = 0; dn < 4; ++dn)
      AO[((size_t)(b*T_ + t))*DM + h*64 + dn*16 + lane16] = f2b(o[dn][r]*ivr[r]);
  }
}

// ---------------- launch ----------------
extern "C" void kernel_launch(void* const* d_in, const int* in_sizes, int n_in,
                              void* d_out, int out_size, void* d_ws, size_t ws_size,
                              hipStream_t stream) {
  const float* x     = (const float*)d_in[0];
  const float* cosT  = (const float*)d_in[1];
  const float* sinT  = (const float*)d_in[2];
  const float* w_qkv = (const float*)d_in[3];
  const float* w_out = (const float*)d_in[4];
  float* out = (float*)d_out;

  char* ws = (char*)d_ws;
  u16* xb    = (u16*)(ws);                      // 16 MB  (8192x1024 bf16)
  u16* wqkvb = (u16*)(ws + 16777216);           // 6 MB   (3072x1024)
  u16* woutb = (u16*)(ws + 23068672);           // 2 MB   (1024x1024)
  u16* AO    = (u16*)(ws + 25165824);           // 16 MB  (8192x1024)
  u16* Kh    = (u16*)(ws + 41943040);           // 16 MB  [BH][T][64]
  u16* Vt    = (u16*)(ws + 58720256);           // 16 MB  [BH][64][T]
  u16* Qh    = (u16*)(ws + 75497472);           // 16 MB  -> total 88 MB

  // 1) convert inputs to bf16
  k_f2b<<<4096, 256, 0, stream>>>(x,     xb,    BT_*DM/8);
  k_f2b<<<1536, 256, 0, stream>>>(w_qkv, wqkvb, F3*DM/8);
  k_f2b<<<512,  256, 0, stream>>>(w_out, woutb, DM*DM/8);

  // 2) fused: qkv GEMM + RoPE + head-split + V-transpose (no qkv intermediate)
  k_gemm_qkv<<<(BT_/128)*(F3/128), 256, 0, stream>>>(xb, wqkvb, cosT, sinT, Qh, Kh, Vt);

  // 3) causal flash attention -> AO [B,T,DM] bf16
  k_attn<<<2048, 256, 0, stream>>>(Qh, Kh, Vt, AO);

  // 4) out = AO @ w_out^T  (f32 out)
  k_gemm_bt<float><<<(BT_/128)*(DM/128), 256, 0, stream>>>(AO, woutb, out, BT_, DM, DM);
}

// Round 6
// 169.748 us; speedup vs baseline: 2.3263x; 1.0568x over previous
//
#include <hip/hip_runtime.h>
#include <hip/hip_bf16.h>

// Problem constants
#define B_  4
#define T_  2048
#define DM  1024
#define NH  16
#define DH  64
#define BT_ (B_*T_)    // 8192
#define F3  (3*DM)     // 3072

typedef unsigned short u16;
typedef float  f32x4  __attribute__((ext_vector_type(4)));
typedef short  short8 __attribute__((ext_vector_type(8)));
typedef __bf16 bf16x8 __attribute__((ext_vector_type(8)));
typedef unsigned short u16x8 __attribute__((ext_vector_type(8)));

__device__ __forceinline__ u16 f2b(float f){
  __hip_bfloat16 h = __float2bfloat16(f);
  return *reinterpret_cast<u16*>(&h);
}
__device__ __forceinline__ float b2f(u16 u){
  __hip_bfloat16 h;
  *reinterpret_cast<u16*>(&h) = u;
  return __bfloat162float(h);
}

__device__ __forceinline__ f32x4 mfma16(short8 a, short8 b, f32x4 c){
  return __builtin_amdgcn_mfma_f32_16x16x32_bf16((bf16x8)a, (bf16x8)b, c, 0, 0, 0);
}

// async global->LDS, 16B per lane; lds dest must be wave-uniform base (+lane*16 implicit)
__device__ __forceinline__ void gll16(const void* g, void* l){
  __builtin_amdgcn_global_load_lds((const __attribute__((address_space(1))) unsigned int*)g,
                                   (__attribute__((address_space(3))) unsigned int*)l,
                                   16, 0, 0);
}

// ---------------- fused f32 -> bf16 convert for all 3 inputs ----------------
#define N8_X  (BT_*DM/8)   // 1048576
#define N8_WQ (F3*DM/8)    // 393216
#define N8_WO (DM*DM/8)    // 131072
__global__ __launch_bounds__(256) void k_f2b3(const float* __restrict__ ax,
                                              const float* __restrict__ aq,
                                              const float* __restrict__ ao,
                                              u16* __restrict__ ox,
                                              u16* __restrict__ oq,
                                              u16* __restrict__ oo){
  int i = blockIdx.x*256 + threadIdx.x;
  const float* src; u16* dst; int k;
  if (i < N8_X)              { src = ax; dst = ox; k = i; }
  else if (i < N8_X + N8_WQ) { src = aq; dst = oq; k = i - N8_X; }
  else                       { src = ao; dst = oo; k = i - (N8_X + N8_WQ); }
  const float4* p = reinterpret_cast<const float4*>(src) + (size_t)k*2;
  float4 a = p[0], b = p[1];
  u16x8 r;
  r[0]=f2b(a.x); r[1]=f2b(a.y); r[2]=f2b(a.z); r[3]=f2b(a.w);
  r[4]=f2b(b.x); r[5]=f2b(b.y); r[6]=f2b(b.z); r[7]=f2b(b.w);
  *(reinterpret_cast<u16x8*>(dst) + k) = r;
}

// ---------------- generic GEMM C = A * B^T (for the output projection) ----------------
template<typename OUT>
__global__ __launch_bounds__(256, 2) void k_gemm_bt(const u16* __restrict__ A,
                                                    const u16* __restrict__ Bm,
                                                    OUT* __restrict__ C,
                                                    int M, int N, int K){
  __shared__ __attribute__((aligned(16))) u16 lA[128*64];
  __shared__ __attribute__((aligned(16))) u16 lB[128*64];

  int nbn = N >> 7;
  int nwg = gridDim.x;
  int bid = blockIdx.x;
  int wg = bid;
  if ((nwg & 7) == 0) { int q = nwg >> 3; wg = (bid & 7)*q + (bid >> 3); } // XCD swizzle
  int bm = wg / nbn, bn = wg % nbn;

  int tid = threadIdx.x, wv = tid >> 6, l = tid & 63;
  int lane16 = l & 15, lg = l >> 4;
  int wr = wv >> 1, wc = wv & 1;

  f32x4 acc[4][4] = {};

  const u16* pA = A + (size_t)(bm*128 + wv*8 + (l>>3))*K + (l&7)*8;
  const u16* pB = Bm + (size_t)(bn*128 + wv*8 + (l>>3))*K + (l&7)*8;
  char* lAb = (char*)lA + wv*1024;
  char* lBb = (char*)lB + wv*1024;

  int nk = K >> 6;
  for (int kt = 0; kt < nk; ++kt){
    const u16* gA = pA + kt*64;
    const u16* gB = pB + kt*64;
    #pragma unroll
    for (int c = 0; c < 4; ++c){
      gll16(gA + (size_t)c*32*K, lAb + c*4096);
      gll16(gB + (size_t)c*32*K, lBb + c*4096);
    }
    __syncthreads();
    #pragma unroll
    for (int kk = 0; kk < 2; ++kk){
      short8 am[4], bb[4];
      #pragma unroll
      for (int m = 0; m < 4; ++m)
        am[m] = *(const short8*)&lA[(wr*64 + m*16 + lane16)*64 + kk*32 + lg*8];
      #pragma unroll
      for (int n = 0; n < 4; ++n)
        bb[n] = *(const short8*)&lB[(wc*64 + n*16 + lane16)*64 + kk*32 + lg*8];
      #pragma unroll
      for (int m = 0; m < 4; ++m)
        #pragma unroll
        for (int n = 0; n < 4; ++n)
          acc[m][n] = mfma16(am[m], bb[n], acc[m][n]);
    }
    __syncthreads();
  }

  #pragma unroll
  for (int m = 0; m < 4; ++m){
    #pragma unroll
    for (int n = 0; n < 4; ++n){
      #pragma unroll
      for (int r = 0; r < 4; ++r){
        int grow = bm*128 + wr*64 + m*16 + lg*4 + r;
        int gcol = bn*128 + wc*64 + n*16 + lane16;
        float v = acc[m][n][r];
        if constexpr (sizeof(OUT) == 2) C[(size_t)grow*N + gcol] = (OUT)f2b(v);
        else                            C[(size_t)grow*N + gcol] = v;
      }
    }
  }
}

// ---------------- QKV GEMM with fused RoPE + head-split + V-transpose epilogue ----
// qkv = x @ w_qkv^T, tiles 128x128. Each wave's 64-col span is exactly one head,
// and the RoPE pair (d, d+32) is (acc n, acc n+2) in the SAME lane. cos/sin tables
// satisfy cos[t][d+32]==cos[t][d], so 2 cos + 2 sin loads per (m,r).
// Q is pre-scaled by (1/8)*log2(e) (attn softmax uses exp2).
// V tiles are transposed through the (idle) staging LDS and stored [bh][d][t].
__global__ __launch_bounds__(256, 2) void k_gemm_qkv(const u16* __restrict__ A,
    const u16* __restrict__ Bm,
    const float* __restrict__ cosT, const float* __restrict__ sinT,
    u16* __restrict__ Qh, u16* __restrict__ Kh, u16* __restrict__ Vt){
  __shared__ __attribute__((aligned(16))) u16 lsmem[2*128*64];  // 32 KB
  u16* lA = lsmem;
  u16* lB = lsmem + 128*64;
  const int K = DM;
  const int nbn = F3 >> 7;   // 24

  int bid = blockIdx.x;
  int q8 = (64*24) >> 3;
  int wg = (bid & 7)*q8 + (bid >> 3);   // XCD swizzle (1536 % 8 == 0)
  int bm = wg / nbn, bn = wg % nbn;

  int tid = threadIdx.x, wv = tid >> 6, l = tid & 63;
  int lane16 = l & 15, lg = l >> 4;
  int wr = wv >> 1, wc = wv & 1;

  f32x4 acc[4][4] = {};

  const u16* pA = A + (size_t)(bm*128 + wv*8 + (l>>3))*K + (l&7)*8;
  const u16* pB = Bm + (size_t)(bn*128 + wv*8 + (l>>3))*K + (l&7)*8;
  char* lAb = (char*)lA + wv*1024;
  char* lBb = (char*)lB + wv*1024;

  int nk = K >> 6;
  for (int kt = 0; kt < nk; ++kt){
    const u16* gA = pA + kt*64;
    const u16* gB = pB + kt*64;
    #pragma unroll
    for (int c = 0; c < 4; ++c){
      gll16(gA + (size_t)c*32*K, lAb + c*4096);
      gll16(gB + (size_t)c*32*K, lBb + c*4096);
    }
    __syncthreads();
    #pragma unroll
    for (int kk = 0; kk < 2; ++kk){
      short8 am[4], bb[4];
      #pragma unroll
      for (int m = 0; m < 4; ++m)
        am[m] = *(const short8*)&lA[(wr*64 + m*16 + lane16)*64 + kk*32 + lg*8];
      #pragma unroll
      for (int n = 0; n < 4; ++n)
        bb[n] = *(const short8*)&lB[(wc*64 + n*16 + lane16)*64 + kk*32 + lg*8];
      #pragma unroll
      for (int m = 0; m < 4; ++m)
        #pragma unroll
        for (int n = 0; n < 4; ++n)
          acc[m][n] = mfma16(am[m], bb[n], acc[m][n]);
    }
    __syncthreads();
  }

  int sect = bn >> 3;          // 0=q, 1=k, 2=v (section boundaries are 128-aligned)
  int t0 = bm*128;
  int b  = t0 >> 11;           // batch (2048 is a multiple of 128)
  int tt0 = t0 & 2047;         // sequence offset within batch

  if (sect < 2){
    u16* dst = sect ? Kh : Qh;
    float scq = sect ? 1.0f : 0.18033688011f;   // (1/8)*log2(e) folded into Q
    int fcol = (bn & 7)*128 + wc*64;            // feature within section, 64-aligned
    int h = fcol >> 6;                          // whole wave in one head
    size_t hrow = (size_t)(b*NH + h)*T_;
    #pragma unroll
    for (int m = 0; m < 4; ++m){
      #pragma unroll
      for (int r = 0; r < 4; ++r){
        int t = tt0 + wr*64 + m*16 + lg*4 + r;
        const float* cp = cosT + (size_t)t*64;
        const float* sp = sinT + (size_t)t*64;
        float c0 = cp[lane16],      s0 = sp[lane16];
        float c1 = cp[16 + lane16], s1 = sp[16 + lane16];
        float a0 = acc[m][0][r], a1 = acc[m][1][r];
        float a2 = acc[m][2][r], a3 = acc[m][3][r];
        size_t base = (hrow + t)*64;
        dst[base + lane16]      = f2b((a0*c0 - a2*s0)*scq);   // d = lane16
        dst[base + 16 + lane16] = f2b((a1*c1 - a3*s1)*scq);   // d = 16+lane16
        dst[base + 32 + lane16] = f2b((a2*c0 + a0*s0)*scq);   // d = 32+lane16
        dst[base + 48 + lane16] = f2b((a3*c1 + a1*s1)*scq);   // d = 48+lane16
      }
    }
  } else {
    // V: transpose 128t x 128f tile -> Vt[bh][d][t], via LDS in two 64-col passes
    int fbase = (bn & 7)*128;
    for (int cc = 0; cc < 2; ++cc){
      __syncthreads();
      if (wc == cc){
        #pragma unroll
        for (int m = 0; m < 4; ++m)
          #pragma unroll
          for (int n = 0; n < 4; ++n)
            #pragma unroll
            for (int r = 0; r < 4; ++r){
              int cl = n*16 + lane16;              // 0..63 (d within head)
              int tl = wr*64 + m*16 + lg*4 + r;    // 0..127
              lsmem[cl*136 + tl] = f2b(acc[m][n][r]);
            }
      }
      __syncthreads();
      int h = (fbase + cc*64) >> 6;
      int dl = tid >> 2, seg = tid & 3;
      const u16* src = lsmem + dl*136 + seg*32;
      u16* dp = Vt + ((size_t)(b*NH + h)*64 + dl)*T_ + tt0 + seg*32;
      *(u16x8*)dp      = *(const u16x8*)src;
      *(u16x8*)(dp+8)  = *(const u16x8*)(src+8);
      *(u16x8*)(dp+16) = *(const u16x8*)(src+16);
      *(u16x8*)(dp+24) = *(const u16x8*)(src+24);
    }
  }
}

// ---------------- causal flash attention ----------------
// 2-buffer depth-1 pipeline: {vmcnt(0); s_barrier; STAGE(it+1); compute(it)} --
// one barrier per tile, loads overlap the whole compute phase, 32 KB LDS ->
// ~4-5 blocks/CU (vs 2 with the old 3-buffer/48KB scheme). KV is XCD-L2-resident
// (grid decode pins all q-blocks of a bh to one XCD) so depth-1 covers latency.
// In-register P via cvt_pk + permlane swaps (distinct-value operands only!);
// defer-max; exp2 softmax (log2e folded into Q upstream). Per-iter cross-lane
// reduction only for MAX; lsum partials reduced once in the epilogue.
__global__ __launch_bounds__(256, 4) void k_attn(const u16* __restrict__ Qh,
    const u16* __restrict__ Kh, const u16* __restrict__ Vt, u16* __restrict__ AO){
  __shared__ __attribute__((aligned(16))) u16 lK[2][64*64];
  __shared__ __attribute__((aligned(16))) u16 lV[2][64*64];

  // bid bits: [2:0]=bh_lo (XCD), [5:3]=bh_hi, [10:6]=31-qt  -> all q-blocks of a
  // bh land on one XCD; big qt dispatched first.
  int bid = (int)blockIdx.x;
  int qt = 31 - (bid >> 6);
  int bh = ((bid >> 3) & 7) * 8 + (bid & 7);
  int q0 = qt*64;
  int b = bh >> 4, h = bh & 15;
  int tid = threadIdx.x, wv = tid >> 6, l = tid & 63;
  int lane16 = l & 15, lg = l >> 4;

  // Q fragments (B-operand of swapped QK^T)
  short8 bq[2];
  const u16* qp = Qh + ((size_t)bh*T_ + q0 + wv*16 + lane16)*64 + lg*8;
  bq[0] = *(const short8*)qp;
  bq[1] = *(const short8*)(qp + 32);

  f32x4 o[4] = {};                       // o[dn][r]: q_local=lg*4+r, d=dn*16+lane16
  float mrow = -INFINITY, lsum = 0.f;    // lsum = per-lane partial (reduced at end)

  const u16* Kb = Kh + (size_t)bh*T_*64;
  const u16* Vb = Vt + (size_t)bh*64*T_;

  int rl = l >> 3;                 // row within 8-row staging group
  int sc = ((l&7) ^ rl) * 8;       // pre-swizzled source column (elements)
  int nt = qt + 1;

  // stage: 4 gll16 per wave (K c0, V c0, K c1, V c1)
  auto STAGE = [&](int tile, int bufi){
    char* kd = (char*)lK[bufi] + wv*1024;
    char* vd = (char*)lV[bufi] + wv*1024;
    const u16* kg = Kb + (size_t)(tile*64 + wv*8 + rl)*64 + sc;
    const u16* vg = Vb + (size_t)(wv*8 + rl)*T_ + tile*64 + sc;
    gll16(kg, kd);
    gll16(vg, vd);
    gll16(kg + 32*64, kd + 4096);
    gll16(vg + (size_t)32*T_, vd + 4096);
  };

  STAGE(0, 0);

  for (int it = 0; it < nt; ++it){
    int cur = it & 1;
    // tile it's 4 loads are the only outstanding ones (tile it+1 not yet issued)
    asm volatile("s_waitcnt vmcnt(0)" ::: "memory");
    __builtin_amdgcn_s_barrier();     // all waves' tile-it writes visible; buf[cur^1] free
    if (it + 1 < nt) STAGE(it + 1, cur ^ 1);

    const char* Kc = (const char*)lK[cur];
    const char* Vc = (const char*)lV[cur];
    int kv0 = it*64;

    // S^T tile: s[n][r] = S[k = kv0+n*16+lg*4+r][q = lane16-row of this wave]
    f32x4 s[4];
    __builtin_amdgcn_s_setprio(1);
    #pragma unroll
    for (int n = 0; n < 4; ++n){
      int row = n*16 + lane16;
      short8 ak0 = *(const short8*)(Kc + row*128 + (((lg    ) ^ (row&7))<<4));
      short8 ak1 = *(const short8*)(Kc + row*128 + (((4 + lg) ^ (row&7))<<4));
      f32x4 z = {};
      z = mfma16(ak0, bq[0], z);
      z = mfma16(ak1, bq[1], z);
      s[n] = z;
    }
    __builtin_amdgcn_s_setprio(0);

    if (it == nt-1){  // only diagonal tile needs masking
      int q_abs = q0 + wv*16 + lane16;
      #pragma unroll
      for (int n = 0; n < 4; ++n)
        #pragma unroll
        for (int r = 0; r < 4; ++r){
          int key = kv0 + n*16 + lg*4 + r;
          if (key > q_abs) s[n][r] = -1e30f;
        }
    }

    // per-q max (q = lane16; 16 values per lane, row spread over lanes ^16,^32)
    float pm = s[0][0];
    #pragma unroll
    for (int n = 0; n < 4; ++n)
      #pragma unroll
      for (int r = 0; r < 4; ++r) pm = fmaxf(pm, s[n][r]);
    pm = fmaxf(pm, __shfl_xor(pm, 16, 64));
    pm = fmaxf(pm, __shfl_xor(pm, 32, 64));

    // defer-max: rescale only when max grew by > 8 (log2 units; P bounded by 2^8)
    if (__any(pm > mrow + 8.f)){
      float mn = fmaxf(mrow, pm);
      float al = __builtin_amdgcn_exp2f(mrow - mn);
      mrow = mn;
      float alr[4];
      #pragma unroll
      for (int r = 0; r < 4; ++r) alr[r] = __shfl(al, (l & 48) | (lg*4 + r), 64);
      #pragma unroll
      for (int dn = 0; dn < 4; ++dn)
        #pragma unroll
        for (int r = 0; r < 4; ++r) o[dn][r] *= alr[r];
      lsum *= al;
    }

    float rs = 0.f;
    #pragma unroll
    for (int n = 0; n < 4; ++n)
      #pragma unroll
      for (int r = 0; r < 4; ++r){
        float p = __builtin_amdgcn_exp2f(s[n][r] - mrow);
        s[n][r] = p; rs += p;
      }
    lsum += rs;   // per-lane partial; cross-lane reduce deferred to epilogue

    // pack P to bf16 in-register: d[n][h] covers k = n*16 + lg*4 + 2h + {0,1}
    unsigned d[4][2];
    #pragma unroll
    for (int n = 0; n < 4; ++n){
      asm("v_cvt_pk_bf16_f32 %0, %1, %2" : "=v"(d[n][0]) : "v"(s[n][0]), "v"(s[n][1]));
      asm("v_cvt_pk_bf16_f32 %0, %1, %2" : "=v"(d[n][1]) : "v"(s[n][2]), "v"(s[n][3]));
    }
    // permute into A-fragment layout: lane (lg) holds P[q=lane16][k=lg*8..+8] (+32 for pa1)
    // pair (d[2g][h], d[2g+1][h]) --swap32--> --swap16--> {slot h, slot 2+h} of pa_g
    // (operands hold DIFFERENT values -> regalloc cannot coalesce them)
    union { unsigned u[4]; short8 v; } pk0, pk1;
    #pragma unroll
    for (int g = 0; g < 2; ++g){
      #pragma unroll
      for (int hh = 0; hh < 2; ++hh){
        unsigned A = d[2*g][hh], Bv = d[2*g+1][hh];
        asm("v_permlane32_swap_b32 %0, %1" : "+v"(A), "+v"(Bv));
        asm("v_permlane16_swap_b32 %0, %1" : "+v"(A), "+v"(Bv));
        if (g == 0){ pk0.u[hh] = A; pk0.u[2+hh] = Bv; }
        else       { pk1.u[hh] = A; pk1.u[2+hh] = Bv; }
      }
    }

    // PV: A = P rows (q=lane16), B = Vt rows (d)
    __builtin_amdgcn_s_setprio(1);
    #pragma unroll
    for (int dn = 0; dn < 4; ++dn){
      int row = dn*16 + lane16;
      short8 bv0 = *(const short8*)(Vc + row*128 + (((lg    ) ^ (row&7))<<4));
      short8 bv1 = *(const short8*)(Vc + row*128 + (((4 + lg) ^ (row&7))<<4));
      o[dn] = mfma16(pk0.v, bv0, o[dn]);
      o[dn] = mfma16(pk1.v, bv1, o[dn]);
    }
    __builtin_amdgcn_s_setprio(0);
  }

  // epilogue: finish the deferred lsum reduction (all 4 lane-groups same q-set)
  lsum += __shfl_xor(lsum, 16, 64);
  lsum += __shfl_xor(lsum, 32, 64);
  float inv = 1.f / lsum;
  float ivr[4];
  #pragma unroll
  for (int r = 0; r < 4; ++r) ivr[r] = __shfl(inv, (l & 48) | (lg*4 + r), 64);
  #pragma unroll
  for (int r = 0; r < 4; ++r){
    int t = q0 + wv*16 + lg*4 + r;
    #pragma unroll
    for (int dn = 0; dn < 4; ++dn)
      AO[((size_t)(b*T_ + t))*DM + h*64 + dn*16 + lane16] = f2b(o[dn][r]*ivr[r]);
  }
}

// ---------------- launch ----------------
extern "C" void kernel_launch(void* const* d_in, const int* in_sizes, int n_in,
                              void* d_out, int out_size, void* d_ws, size_t ws_size,
                              hipStream_t stream) {
  const float* x     = (const float*)d_in[0];
  const float* cosT  = (const float*)d_in[1];
  const float* sinT  = (const float*)d_in[2];
  const float* w_qkv = (const float*)d_in[3];
  const float* w_out = (const float*)d_in[4];
  float* out = (float*)d_out;

  char* ws = (char*)d_ws;
  u16* xb    = (u16*)(ws);                      // 16 MB  (8192x1024 bf16)
  u16* wqkvb = (u16*)(ws + 16777216);           // 6 MB   (3072x1024)
  u16* woutb = (u16*)(ws + 23068672);           // 2 MB   (1024x1024)
  u16* AO    = (u16*)(ws + 25165824);           // 16 MB  (8192x1024)
  u16* Kh    = (u16*)(ws + 41943040);           // 16 MB  [BH][T][64]
  u16* Vt    = (u16*)(ws + 58720256);           // 16 MB  [BH][64][T]
  u16* Qh    = (u16*)(ws + 75497472);           // 16 MB  -> total 88 MB

  // 1) convert all inputs to bf16 (single fused launch)
  k_f2b3<<<(N8_X+N8_WQ+N8_WO)/256, 256, 0, stream>>>(x, w_qkv, w_out, xb, wqkvb, woutb);

  // 2) fused: qkv GEMM + RoPE + head-split + V-transpose (no qkv intermediate)
  k_gemm_qkv<<<(BT_/128)*(F3/128), 256, 0, stream>>>(xb, wqkvb, cosT, sinT, Qh, Kh, Vt);

  // 3) causal flash attention -> AO [B,T,DM] bf16
  k_attn<<<2048, 256, 0, stream>>>(Qh, Kh, Vt, AO);

  // 4) out = AO @ w_out^T  (f32 out)
  k_gemm_bt<float><<<(BT_/128)*(DM/128), 256, 0, stream>>>(AO, woutb, out, BT_, DM, DM);
}

// Round 7
// 169.211 us; speedup vs baseline: 2.3337x; 1.0032x over previous
//
#include <hip/hip_runtime.h>
#include <hip/hip_bf16.h>

// Problem constants
#define B_  4
#define T_  2048
#define DM  1024
#define NH  16
#define DH  64
#define BT_ (B_*T_)    // 8192
#define F3  (3*DM)     // 3072

typedef unsigned short u16;
typedef float  f32x4  __attribute__((ext_vector_type(4)));
typedef short  short8 __attribute__((ext_vector_type(8)));
typedef __bf16 bf16x8 __attribute__((ext_vector_type(8)));
typedef unsigned short u16x8 __attribute__((ext_vector_type(8)));

__device__ __forceinline__ u16 f2b(float f){
  __hip_bfloat16 h = __float2bfloat16(f);
  return *reinterpret_cast<u16*>(&h);
}
__device__ __forceinline__ float b2f(u16 u){
  __hip_bfloat16 h;
  *reinterpret_cast<u16*>(&h) = u;
  return __bfloat162float(h);
}

__device__ __forceinline__ f32x4 mfma16(short8 a, short8 b, f32x4 c){
  return __builtin_amdgcn_mfma_f32_16x16x32_bf16((bf16x8)a, (bf16x8)b, c, 0, 0, 0);
}

// async global->LDS, 16B per lane; lds dest must be wave-uniform base (+lane*16 implicit)
__device__ __forceinline__ void gll16(const void* g, void* l){
  __builtin_amdgcn_global_load_lds((const __attribute__((address_space(1))) unsigned int*)g,
                                   (__attribute__((address_space(3))) unsigned int*)l,
                                   16, 0, 0);
}

#define BARRIER  __builtin_amdgcn_s_barrier()
#define LGKM0    asm volatile("s_waitcnt lgkmcnt(0)" ::: "memory")

// ---------------- fused f32 -> bf16 convert for all 3 inputs ----------------
#define N8_X  (BT_*DM/8)   // 1048576
#define N8_WQ (F3*DM/8)    // 393216
#define N8_WO (DM*DM/8)    // 131072
__global__ __launch_bounds__(256) void k_f2b3(const float* __restrict__ ax,
                                              const float* __restrict__ aq,
                                              const float* __restrict__ ao,
                                              u16* __restrict__ ox,
                                              u16* __restrict__ oq,
                                              u16* __restrict__ oo){
  int i = blockIdx.x*256 + threadIdx.x;
  const float* src; u16* dst; int k;
  if (i < N8_X)              { src = ax; dst = ox; k = i; }
  else if (i < N8_X + N8_WQ) { src = aq; dst = oq; k = i - N8_X; }
  else                       { src = ao; dst = oo; k = i - (N8_X + N8_WQ); }
  const float4* p = reinterpret_cast<const float4*>(src) + (size_t)k*2;
  float4 a = p[0], b = p[1];
  u16x8 r;
  r[0]=f2b(a.x); r[1]=f2b(a.y); r[2]=f2b(a.z); r[3]=f2b(a.w);
  r[4]=f2b(b.x); r[5]=f2b(b.y); r[6]=f2b(b.z); r[7]=f2b(b.w);
  *(reinterpret_cast<u16x8*>(dst) + k) = r;
}

// ---------------- generic GEMM C = A * B^T (for the output projection) ----------------
template<typename OUT>
__global__ __launch_bounds__(256, 2) void k_gemm_bt(const u16* __restrict__ A,
                                                    const u16* __restrict__ Bm,
                                                    OUT* __restrict__ C,
                                                    int M, int N, int K){
  __shared__ __attribute__((aligned(16))) u16 lA[128*64];
  __shared__ __attribute__((aligned(16))) u16 lB[128*64];

  int nbn = N >> 7;
  int nwg = gridDim.x;
  int bid = blockIdx.x;
  int wg = bid;
  if ((nwg & 7) == 0) { int q = nwg >> 3; wg = (bid & 7)*q + (bid >> 3); } // XCD swizzle
  int bm = wg / nbn, bn = wg % nbn;

  int tid = threadIdx.x, wv = tid >> 6, l = tid & 63;
  int lane16 = l & 15, lg = l >> 4;
  int wr = wv >> 1, wc = wv & 1;

  f32x4 acc[4][4] = {};

  const u16* pA = A + (size_t)(bm*128 + wv*8 + (l>>3))*K + (l&7)*8;
  const u16* pB = Bm + (size_t)(bn*128 + wv*8 + (l>>3))*K + (l&7)*8;
  char* lAb = (char*)lA + wv*1024;
  char* lBb = (char*)lB + wv*1024;

  int nk = K >> 6;
  for (int kt = 0; kt < nk; ++kt){
    const u16* gA = pA + kt*64;
    const u16* gB = pB + kt*64;
    #pragma unroll
    for (int c = 0; c < 4; ++c){
      gll16(gA + (size_t)c*32*K, lAb + c*4096);
      gll16(gB + (size_t)c*32*K, lBb + c*4096);
    }
    __syncthreads();
    #pragma unroll
    for (int kk = 0; kk < 2; ++kk){
      short8 am[4], bb[4];
      #pragma unroll
      for (int m = 0; m < 4; ++m)
        am[m] = *(const short8*)&lA[(wr*64 + m*16 + lane16)*64 + kk*32 + lg*8];
      #pragma unroll
      for (int n = 0; n < 4; ++n)
        bb[n] = *(const short8*)&lB[(wc*64 + n*16 + lane16)*64 + kk*32 + lg*8];
      #pragma unroll
      for (int m = 0; m < 4; ++m)
        #pragma unroll
        for (int n = 0; n < 4; ++n)
          acc[m][n] = mfma16(am[m], bb[n], acc[m][n]);
    }
    __syncthreads();
  }

  #pragma unroll
  for (int m = 0; m < 4; ++m){
    #pragma unroll
    for (int n = 0; n < 4; ++n){
      #pragma unroll
      for (int r = 0; r < 4; ++r){
        int grow = bm*128 + wr*64 + m*16 + lg*4 + r;
        int gcol = bn*128 + wc*64 + n*16 + lane16;
        float v = acc[m][n][r];
        if constexpr (sizeof(OUT) == 2) C[(size_t)grow*N + gcol] = (OUT)f2b(v);
        else                            C[(size_t)grow*N + gcol] = v;
      }
    }
  }
}

// ---------------- QKV GEMM: 256x256 8-phase template + fused RoPE/V-transpose ----
// qkv = x @ w_qkv^T. BM=BN=256, BK=64, 512 threads = 8 waves (2M x 4N).
// Per-wave C: 128x64 = acc[8][4]. LDS: 2 dbuf x (A 32KB + B 32KB) = 128 KB,
// chunk-XOR swizzled via pre-swizzled global_load_lds source (read XORs same).
// 8 phases per 2 K-tiles; each phase: {ds_read subtile | stage 1 half-tile |
// barrier | lgkm0 | 16 MFMA | barrier}; counted vmcnt(4) at phases 4 and 8 only
// (stage order: A-halves of next tile in ph 1-2/5-6, B-halves of tile+2 in ph
// 3-4/7-8 -> each vmcnt leaves exactly the newest 4 loads outstanding).
// Last iter: stages beyond K-tile 15 skipped -> counted N invalid -> vmcnt(0).
// Epilogue: RoPE (q/k sections; pair d<->d+32 = acc n<->n+2, same lane) or
// V-transpose via 135KB LDS overlay -> Vt[bh][d][t].
__global__ __launch_bounds__(512, 1) void k_gemm_qkv(const u16* __restrict__ A,
    const u16* __restrict__ Bm,
    const float* __restrict__ cosT, const float* __restrict__ sinT,
    u16* __restrict__ Qh, u16* __restrict__ Kh, u16* __restrict__ Vt){
  __shared__ __attribute__((aligned(16))) char smem[135168];  // 128K stage | 132K V-ovl
  char* lA0 = smem;           char* lA1 = smem + 32768;
  char* lB0 = smem + 65536;   char* lB1 = smem + 98304;

  int bid = (int)blockIdx.x;
  int wg = (bid & 7)*48 + (bid >> 3);   // XCD swizzle (384 = 8*48)
  int bm = wg / 12, bn = wg % 12;

  int tid = threadIdx.x, wv = tid >> 6, l = tid & 63;
  int lane16 = l & 15, lg = l >> 4;
  int wm = wv >> 2, wn = wv & 3;
  int rl = l >> 3;
  int sc = ((l & 7) ^ rl) * 8;          // pre-swizzled source column (u16)

  const u16* Ag = A  + (size_t)(bm*256 + wv*8 + rl)*DM + sc;
  const u16* Bg = Bm + (size_t)(bn*256 + wv*8 + rl)*DM + sc;

  // stage half-tile h (128 rows) of K-tile t into lbase: 2 gll16/wave
  auto SG = [&](const u16* gbase, char* lbase, int h, int t){
    const u16* g = gbase + (size_t)h*128*DM + t*64;
    char* ld = lbase + h*16384 + wv*1024;
    gll16(g, ld);
    gll16(g + (size_t)64*DM, ld + 8192);
  };
  // swizzled ds_read_b128 of tile row `row`, k-chunk kk*32+lg*8
  auto RD = [&](const char* base, int row, int kk) -> short8 {
    return *(const short8*)(base + row*128 + (((kk*4 + lg) ^ (row & 7)) << 4));
  };

  f32x4 acc[8][4] = {};
  short8 am[4][2], bb[4][2];
  int ra = wm*128 + lane16;
  int rb = wn*64  + lane16;

  auto MF8 = [&](int mb, int n0){
    #pragma unroll
    for (int m = 0; m < 4; ++m)
      #pragma unroll
      for (int nn = 0; nn < 2; ++nn){
        int n = n0 + nn;
        acc[mb+m][n] = mfma16(am[m][0], bb[n][0], acc[mb+m][n]);
        acc[mb+m][n] = mfma16(am[m][1], bb[n][1], acc[mb+m][n]);
      }
  };

  // prologue: B0(0),B1(0),A0(0),A1(0),B0(1),B1(1); allow newest 4 outstanding
  SG(Bg,lB0,0,0); SG(Bg,lB0,1,0); SG(Ag,lA0,0,0); SG(Ag,lA0,1,0);
  SG(Bg,lB1,0,1); SG(Bg,lB1,1,1);
  asm volatile("s_waitcnt vmcnt(4)" ::: "memory");
  BARRIER;

  #pragma unroll 1
  for (int i = 0; i < 8; ++i){
    bool last = (i == 7);
    int t1 = 2*i + 1;
    // ---- phase 1: tile 2i Q0 (m0-3 x n0-1) ----
    #pragma unroll
    for (int m = 0; m < 4; ++m){ am[m][0]=RD(lA0, ra+m*16, 0); am[m][1]=RD(lA0, ra+m*16, 1); }
    #pragma unroll
    for (int n = 0; n < 2; ++n){ bb[n][0]=RD(lB0, rb+n*16, 0); bb[n][1]=RD(lB0, rb+n*16, 1); }
    SG(Ag, lA1, 0, t1);
    BARRIER; LGKM0;
    __builtin_amdgcn_s_setprio(1); MF8(0,0); __builtin_amdgcn_s_setprio(0);
    BARRIER;
    // ---- phase 2: Q1 (m0-3 x n2-3) ----
    #pragma unroll
    for (int n = 2; n < 4; ++n){ bb[n][0]=RD(lB0, rb+n*16, 0); bb[n][1]=RD(lB0, rb+n*16, 1); }
    SG(Ag, lA1, 1, t1);
    BARRIER; LGKM0;
    __builtin_amdgcn_s_setprio(1); MF8(0,2); __builtin_amdgcn_s_setprio(0);
    BARRIER;
    // ---- phase 3: Q2 (m4-7 x n0-1) ----
    #pragma unroll
    for (int m = 0; m < 4; ++m){ am[m][0]=RD(lA0, ra+64+m*16, 0); am[m][1]=RD(lA0, ra+64+m*16, 1); }
    if (!last) SG(Bg, lB0, 0, 2*i+2);
    BARRIER; LGKM0;
    __builtin_amdgcn_s_setprio(1); MF8(4,0); __builtin_amdgcn_s_setprio(0);
    BARRIER;
    // ---- phase 4: Q3 (m4-7 x n2-3), vmcnt covers tile 2i+1 ----
    if (!last) SG(Bg, lB0, 1, 2*i+2);
    if (last) asm volatile("s_waitcnt vmcnt(0)" ::: "memory");
    else      asm volatile("s_waitcnt vmcnt(4)" ::: "memory");
    BARRIER;
    __builtin_amdgcn_s_setprio(1); MF8(4,2); __builtin_amdgcn_s_setprio(0);
    BARRIER;
    // ---- phase 5: tile 2i+1 Q0 ----
    #pragma unroll
    for (int m = 0; m < 4; ++m){ am[m][0]=RD(lA1, ra+m*16, 0); am[m][1]=RD(lA1, ra+m*16, 1); }
    #pragma unroll
    for (int n = 0; n < 2; ++n){ bb[n][0]=RD(lB1, rb+n*16, 0); bb[n][1]=RD(lB1, rb+n*16, 1); }
    if (!last) SG(Ag, lA0, 0, 2*i+2);
    BARRIER; LGKM0;
    __builtin_amdgcn_s_setprio(1); MF8(0,0); __builtin_amdgcn_s_setprio(0);
    BARRIER;
    // ---- phase 6: Q1 ----
    #pragma unroll
    for (int n = 2; n < 4; ++n){ bb[n][0]=RD(lB1, rb+n*16, 0); bb[n][1]=RD(lB1, rb+n*16, 1); }
    if (!last) SG(Ag, lA0, 1, 2*i+2);
    BARRIER; LGKM0;
    __builtin_amdgcn_s_setprio(1); MF8(0,2); __builtin_amdgcn_s_setprio(0);
    BARRIER;
    // ---- phase 7: Q2 ----
    #pragma unroll
    for (int m = 0; m < 4; ++m){ am[m][0]=RD(lA1, ra+64+m*16, 0); am[m][1]=RD(lA1, ra+64+m*16, 1); }
    if (!last) SG(Bg, lB1, 0, 2*i+3);
    BARRIER; LGKM0;
    __builtin_amdgcn_s_setprio(1); MF8(4,0); __builtin_amdgcn_s_setprio(0);
    BARRIER;
    // ---- phase 8: Q3, vmcnt covers tile 2i+2 ----
    if (!last){
      SG(Bg, lB1, 1, 2*i+3);
      asm volatile("s_waitcnt vmcnt(4)" ::: "memory");
    }
    BARRIER;
    __builtin_amdgcn_s_setprio(1); MF8(4,2); __builtin_amdgcn_s_setprio(0);
    BARRIER;
  }

  // ---------------- epilogue ----------------
  int sect = bn >> 2;                 // 0=q, 1=k, 2=v
  int b2  = (bm*256) >> 11;           // batch (256 | 2048)
  int ttb = (bm*256) & 2047;          // seq offset of tile
  if (sect < 2){
    u16* dst = sect ? Kh : Qh;
    float scq = sect ? 1.0f : 0.18033688011f;   // (1/8)*log2(e) folded into Q
    int h = (bn & 3)*4 + wn;                    // whole wave in one head
    size_t hrow = (size_t)(b2*NH + h)*T_;
    #pragma unroll
    for (int m = 0; m < 8; ++m){
      #pragma unroll
      for (int r = 0; r < 4; ++r){
        int t = ttb + wm*128 + m*16 + lg*4 + r;
        const float* cp = cosT + (size_t)t*64;
        const float* sp = sinT + (size_t)t*64;
        float c0 = cp[lane16],      s0 = sp[lane16];
        float c1 = cp[16 + lane16], s1 = sp[16 + lane16];
        float a0 = acc[m][0][r], a1 = acc[m][1][r];
        float a2 = acc[m][2][r], a3 = acc[m][3][r];
        size_t base = (hrow + t)*64;
        dst[base + lane16]      = f2b((a0*c0 - a2*s0)*scq);
        dst[base + 16 + lane16] = f2b((a1*c1 - a3*s1)*scq);
        dst[base + 32 + lane16] = f2b((a2*c0 + a0*s0)*scq);
        dst[base + 48 + lane16] = f2b((a3*c1 + a1*s1)*scq);
      }
    }
  } else {
    // V: 256x256 tile -> Vt[bh][d][t] via LDS overlay [256 cols][264] u16
    __syncthreads();
    u16* vb = (u16*)smem;
    int rowb = wm*128 + lg*4;
    #pragma unroll
    for (int m = 0; m < 8; ++m){
      #pragma unroll
      for (int n = 0; n < 4; ++n){
        int col = wn*64 + n*16 + lane16;
        unsigned lo, hi;
        asm("v_cvt_pk_bf16_f32 %0, %1, %2" : "=v"(lo) : "v"(acc[m][n][0]), "v"(acc[m][n][1]));
        asm("v_cvt_pk_bf16_f32 %0, %1, %2" : "=v"(hi) : "v"(acc[m][n][2]), "v"(acc[m][n][3]));
        unsigned long long w = ((unsigned long long)hi << 32) | (unsigned long long)lo;
        *(unsigned long long*)(vb + (size_t)col*264 + rowb + m*16) = w;
      }
    }
    __syncthreads();
    int col = tid >> 1, hf = tid & 1;
    int h = (bn & 3)*4 + (col >> 6);
    int d = col & 63;
    const u16* src = vb + (size_t)col*264 + hf*128;
    u16* dp = Vt + ((size_t)(b2*NH + h)*64 + d)*T_ + ttb + hf*128;
    #pragma unroll
    for (int j = 0; j < 16; ++j)
      *(u16x8*)(dp + j*8) = *(const u16x8*)(src + j*8);
  }
}

// ---------------- causal flash attention ----------------
// 2-buffer depth-1 pipeline: {vmcnt(0); s_barrier; STAGE(it+1); compute(it)}.
// In-register P via cvt_pk + permlane swaps (distinct-value operands only!);
// defer-max; exp2 softmax (log2e folded into Q upstream). Per-iter cross-lane
// reduction only for MAX; lsum partials reduced once in the epilogue.
__global__ __launch_bounds__(256, 4) void k_attn(const u16* __restrict__ Qh,
    const u16* __restrict__ Kh, const u16* __restrict__ Vt, u16* __restrict__ AO){
  __shared__ __attribute__((aligned(16))) u16 lK[2][64*64];
  __shared__ __attribute__((aligned(16))) u16 lV[2][64*64];

  // bid bits: [2:0]=bh_lo (XCD), [5:3]=bh_hi, [10:6]=31-qt
  int bid = (int)blockIdx.x;
  int qt = 31 - (bid >> 6);
  int bh = ((bid >> 3) & 7) * 8 + (bid & 7);
  int q0 = qt*64;
  int b = bh >> 4, h = bh & 15;
  int tid = threadIdx.x, wv = tid >> 6, l = tid & 63;
  int lane16 = l & 15, lg = l >> 4;

  short8 bq[2];
  const u16* qp = Qh + ((size_t)bh*T_ + q0 + wv*16 + lane16)*64 + lg*8;
  bq[0] = *(const short8*)qp;
  bq[1] = *(const short8*)(qp + 32);

  f32x4 o[4] = {};
  float mrow = -INFINITY, lsum = 0.f;

  const u16* Kb = Kh + (size_t)bh*T_*64;
  const u16* Vb = Vt + (size_t)bh*64*T_;

  int rl = l >> 3;
  int sc = ((l&7) ^ rl) * 8;
  int nt = qt + 1;

  auto STAGE = [&](int tile, int bufi){
    char* kd = (char*)lK[bufi] + wv*1024;
    char* vd = (char*)lV[bufi] + wv*1024;
    const u16* kg = Kb + (size_t)(tile*64 + wv*8 + rl)*64 + sc;
    const u16* vg = Vb + (size_t)(wv*8 + rl)*T_ + tile*64 + sc;
    gll16(kg, kd);
    gll16(vg, vd);
    gll16(kg + 32*64, kd + 4096);
    gll16(vg + (size_t)32*T_, vd + 4096);
  };

  STAGE(0, 0);

  for (int it = 0; it < nt; ++it){
    int cur = it & 1;
    asm volatile("s_waitcnt vmcnt(0)" ::: "memory");
    __builtin_amdgcn_s_barrier();
    if (it + 1 < nt) STAGE(it + 1, cur ^ 1);

    const char* Kc = (const char*)lK[cur];
    const char* Vc = (const char*)lV[cur];
    int kv0 = it*64;

    f32x4 s[4];
    __builtin_amdgcn_s_setprio(1);
    #pragma unroll
    for (int n = 0; n < 4; ++n){
      int row = n*16 + lane16;
      short8 ak0 = *(const short8*)(Kc + row*128 + (((lg    ) ^ (row&7))<<4));
      short8 ak1 = *(const short8*)(Kc + row*128 + (((4 + lg) ^ (row&7))<<4));
      f32x4 z = {};
      z = mfma16(ak0, bq[0], z);
      z = mfma16(ak1, bq[1], z);
      s[n] = z;
    }
    __builtin_amdgcn_s_setprio(0);

    if (it == nt-1){
      int q_abs = q0 + wv*16 + lane16;
      #pragma unroll
      for (int n = 0; n < 4; ++n)
        #pragma unroll
        for (int r = 0; r < 4; ++r){
          int key = kv0 + n*16 + lg*4 + r;
          if (key > q_abs) s[n][r] = -1e30f;
        }
    }

    float pm = s[0][0];
    #pragma unroll
    for (int n = 0; n < 4; ++n)
      #pragma unroll
      for (int r = 0; r < 4; ++r) pm = fmaxf(pm, s[n][r]);
    pm = fmaxf(pm, __shfl_xor(pm, 16, 64));
    pm = fmaxf(pm, __shfl_xor(pm, 32, 64));

    if (__any(pm > mrow + 8.f)){
      float mn = fmaxf(mrow, pm);
      float al = __builtin_amdgcn_exp2f(mrow - mn);
      mrow = mn;
      float alr[4];
      #pragma unroll
      for (int r = 0; r < 4; ++r) alr[r] = __shfl(al, (l & 48) | (lg*4 + r), 64);
      #pragma unroll
      for (int dn = 0; dn < 4; ++dn)
        #pragma unroll
        for (int r = 0; r < 4; ++r) o[dn][r] *= alr[r];
      lsum *= al;
    }

    float rs = 0.f;
    #pragma unroll
    for (int n = 0; n < 4; ++n)
      #pragma unroll
      for (int r = 0; r < 4; ++r){
        float p = __builtin_amdgcn_exp2f(s[n][r] - mrow);
        s[n][r] = p; rs += p;
      }
    lsum += rs;

    unsigned d[4][2];
    #pragma unroll
    for (int n = 0; n < 4; ++n){
      asm("v_cvt_pk_bf16_f32 %0, %1, %2" : "=v"(d[n][0]) : "v"(s[n][0]), "v"(s[n][1]));
      asm("v_cvt_pk_bf16_f32 %0, %1, %2" : "=v"(d[n][1]) : "v"(s[n][2]), "v"(s[n][3]));
    }
    union { unsigned u[4]; short8 v; } pk0, pk1;
    #pragma unroll
    for (int g = 0; g < 2; ++g){
      #pragma unroll
      for (int hh = 0; hh < 2; ++hh){
        unsigned A = d[2*g][hh], Bv = d[2*g+1][hh];
        asm("v_permlane32_swap_b32 %0, %1" : "+v"(A), "+v"(Bv));
        asm("v_permlane16_swap_b32 %0, %1" : "+v"(A), "+v"(Bv));
        if (g == 0){ pk0.u[hh] = A; pk0.u[2+hh] = Bv; }
        else       { pk1.u[hh] = A; pk1.u[2+hh] = Bv; }
      }
    }

    __builtin_amdgcn_s_setprio(1);
    #pragma unroll
    for (int dn = 0; dn < 4; ++dn){
      int row = dn*16 + lane16;
      short8 bv0 = *(const short8*)(Vc + row*128 + (((lg    ) ^ (row&7))<<4));
      short8 bv1 = *(const short8*)(Vc + row*128 + (((4 + lg) ^ (row&7))<<4));
      o[dn] = mfma16(pk0.v, bv0, o[dn]);
      o[dn] = mfma16(pk1.v, bv1, o[dn]);
    }
    __builtin_amdgcn_s_setprio(0);
  }

  lsum += __shfl_xor(lsum, 16, 64);
  lsum += __shfl_xor(lsum, 32, 64);
  float inv = 1.f / lsum;
  float ivr[4];
  #pragma unroll
  for (int r = 0; r < 4; ++r) ivr[r] = __shfl(inv, (l & 48) | (lg*4 + r), 64);
  #pragma unroll
  for (int r = 0; r < 4; ++r){
    int t = q0 + wv*16 + lg*4 + r;
    #pragma unroll
    for (int dn = 0; dn < 4; ++dn)
      AO[((size_t)(b*T_ + t))*DM + h*64 + dn*16 + lane16] = f2b(o[dn][r]*ivr[r]);
  }
}

// ---------------- launch ----------------
extern "C" void kernel_launch(void* const* d_in, const int* in_sizes, int n_in,
                              void* d_out, int out_size, void* d_ws, size_t ws_size,
                              hipStream_t stream) {
  const float* x     = (const float*)d_in[0];
  const float* cosT  = (const float*)d_in[1];
  const float* sinT  = (const float*)d_in[2];
  const float* w_qkv = (const float*)d_in[3];
  const float* w_out = (const float*)d_in[4];
  float* out = (float*)d_out;

  char* ws = (char*)d_ws;
  u16* xb    = (u16*)(ws);                      // 16 MB  (8192x1024 bf16)
  u16* wqkvb = (u16*)(ws + 16777216);           // 6 MB   (3072x1024)
  u16* woutb = (u16*)(ws + 23068672);           // 2 MB   (1024x1024)
  u16* AO    = (u16*)(ws + 25165824);           // 16 MB  (8192x1024)
  u16* Kh    = (u16*)(ws + 41943040);           // 16 MB  [BH][T][64]
  u16* Vt    = (u16*)(ws + 58720256);           // 16 MB  [BH][64][T]
  u16* Qh    = (u16*)(ws + 75497472);           // 16 MB  -> total 88 MB

  // 1) convert all inputs to bf16 (single fused launch)
  k_f2b3<<<(N8_X+N8_WQ+N8_WO)/256, 256, 0, stream>>>(x, w_qkv, w_out, xb, wqkvb, woutb);

  // 2) fused: qkv GEMM (256^2 8-phase) + RoPE + head-split + V-transpose
  k_gemm_qkv<<<(BT_/256)*(F3/256), 512, 0, stream>>>(xb, wqkvb, cosT, sinT, Qh, Kh, Vt);

  // 3) causal flash attention -> AO [B,T,DM] bf16
  k_attn<<<2048, 256, 0, stream>>>(Qh, Kh, Vt, AO);

  // 4) out = AO @ w_out^T  (f32 out)
  k_gemm_bt<float><<<(BT_/128)*(DM/128), 256, 0, stream>>>(AO, woutb, out, BT_, DM, DM);
}

// Round 8
// 166.967 us; speedup vs baseline: 2.3651x; 1.0134x over previous
//
#include <hip/hip_runtime.h>
#include <hip/hip_bf16.h>

// Problem constants
#define B_  4
#define T_  2048
#define DM  1024
#define NH  16
#define DH  64
#define BT_ (B_*T_)    // 8192
#define F3  (3*DM)     // 3072

typedef unsigned short u16;
typedef float  f32x4  __attribute__((ext_vector_type(4)));
typedef short  short8 __attribute__((ext_vector_type(8)));
typedef __bf16 bf16x8 __attribute__((ext_vector_type(8)));
typedef unsigned short u16x8 __attribute__((ext_vector_type(8)));

__device__ __forceinline__ u16 f2b(float f){
  __hip_bfloat16 h = __float2bfloat16(f);
  return *reinterpret_cast<u16*>(&h);
}
__device__ __forceinline__ float b2f(u16 u){
  __hip_bfloat16 h;
  *reinterpret_cast<u16*>(&h) = u;
  return __bfloat162float(h);
}

__device__ __forceinline__ f32x4 mfma16(short8 a, short8 b, f32x4 c){
  return __builtin_amdgcn_mfma_f32_16x16x32_bf16((bf16x8)a, (bf16x8)b, c, 0, 0, 0);
}

// async global->LDS, 16B per lane; lds dest must be wave-uniform base (+lane*16 implicit)
__device__ __forceinline__ void gll16(const void* g, void* l){
  __builtin_amdgcn_global_load_lds((const __attribute__((address_space(1))) unsigned int*)g,
                                   (__attribute__((address_space(3))) unsigned int*)l,
                                   16, 0, 0);
}

#define BARRIER  __builtin_amdgcn_s_barrier()
#define LGKM0    asm volatile("s_waitcnt lgkmcnt(0)" ::: "memory")

// ---------------- fused f32 -> bf16 convert for all 3 inputs ----------------
#define N8_X  (BT_*DM/8)   // 1048576
#define N8_WQ (F3*DM/8)    // 393216
#define N8_WO (DM*DM/8)    // 131072
__global__ __launch_bounds__(256) void k_f2b3(const float* __restrict__ ax,
                                              const float* __restrict__ aq,
                                              const float* __restrict__ ao,
                                              u16* __restrict__ ox,
                                              u16* __restrict__ oq,
                                              u16* __restrict__ oo){
  int i = blockIdx.x*256 + threadIdx.x;
  const float* src; u16* dst; int k;
  if (i < N8_X)              { src = ax; dst = ox; k = i; }
  else if (i < N8_X + N8_WQ) { src = aq; dst = oq; k = i - N8_X; }
  else                       { src = ao; dst = oo; k = i - (N8_X + N8_WQ); }
  const float4* p = reinterpret_cast<const float4*>(src) + (size_t)k*2;
  float4 a = p[0], b = p[1];
  u16x8 r;
  r[0]=f2b(a.x); r[1]=f2b(a.y); r[2]=f2b(a.z); r[3]=f2b(a.w);
  r[4]=f2b(b.x); r[5]=f2b(b.y); r[6]=f2b(b.z); r[7]=f2b(b.w);
  *(reinterpret_cast<u16x8*>(dst) + k) = r;
}

// ---------------- generic GEMM C = A * B^T (V projection + output projection) ----
template<typename OUT>
__global__ __launch_bounds__(256, 2) void k_gemm_bt(const u16* __restrict__ A,
                                                    const u16* __restrict__ Bm,
                                                    OUT* __restrict__ C,
                                                    int M, int N, int K){
  __shared__ __attribute__((aligned(16))) u16 lA[128*64];
  __shared__ __attribute__((aligned(16))) u16 lB[128*64];

  int nbn = N >> 7;
  int nwg = gridDim.x;
  int bid = blockIdx.x;
  int wg = bid;
  if ((nwg & 7) == 0) { int q = nwg >> 3; wg = (bid & 7)*q + (bid >> 3); } // XCD swizzle
  int bm = wg / nbn, bn = wg % nbn;

  int tid = threadIdx.x, wv = tid >> 6, l = tid & 63;
  int lane16 = l & 15, lg = l >> 4;
  int wr = wv >> 1, wc = wv & 1;

  f32x4 acc[4][4] = {};

  const u16* pA = A + (size_t)(bm*128 + wv*8 + (l>>3))*K + (l&7)*8;
  const u16* pB = Bm + (size_t)(bn*128 + wv*8 + (l>>3))*K + (l&7)*8;
  char* lAb = (char*)lA + wv*1024;
  char* lBb = (char*)lB + wv*1024;

  int nk = K >> 6;
  for (int kt = 0; kt < nk; ++kt){
    const u16* gA = pA + kt*64;
    const u16* gB = pB + kt*64;
    #pragma unroll
    for (int c = 0; c < 4; ++c){
      gll16(gA + (size_t)c*32*K, lAb + c*4096);
      gll16(gB + (size_t)c*32*K, lBb + c*4096);
    }
    __syncthreads();
    #pragma unroll
    for (int kk = 0; kk < 2; ++kk){
      short8 am[4], bb[4];
      #pragma unroll
      for (int m = 0; m < 4; ++m)
        am[m] = *(const short8*)&lA[(wr*64 + m*16 + lane16)*64 + kk*32 + lg*8];
      #pragma unroll
      for (int n = 0; n < 4; ++n)
        bb[n] = *(const short8*)&lB[(wc*64 + n*16 + lane16)*64 + kk*32 + lg*8];
      #pragma unroll
      for (int m = 0; m < 4; ++m)
        #pragma unroll
        for (int n = 0; n < 4; ++n)
          acc[m][n] = mfma16(am[m], bb[n], acc[m][n]);
    }
    __syncthreads();
  }

  #pragma unroll
  for (int m = 0; m < 4; ++m){
    #pragma unroll
    for (int n = 0; n < 4; ++n){
      #pragma unroll
      for (int r = 0; r < 4; ++r){
        int grow = bm*128 + wr*64 + m*16 + lg*4 + r;
        int gcol = bn*128 + wc*64 + n*16 + lane16;
        float v = acc[m][n][r];
        if constexpr (sizeof(OUT) == 2) C[(size_t)grow*N + gcol] = (OUT)f2b(v);
        else                            C[(size_t)grow*N + gcol] = v;
      }
    }
  }
}

// ---------------- Q|K GEMM: 256x256 8-phase + fused RoPE epilogue ----------------
// Computes only the q,k sections (w_qkv rows 0..2047): grid = 32x8 = 256 blocks
// = EXACTLY one dispatch pass at 1 block/CU (the R7 384-block version wasted a
// half-empty second pass). V is a separate transposed GEMM (k_gemm_bt).
// BM=BN=256, BK=64, 512 threads = 8 waves (2M x 4N); per-wave C = 128x64 =
// acc[8][4]. LDS 128 KB (2 dbuf x (A 32K + B 32K)), chunk-XOR swizzle via
// pre-swizzled global_load_lds source. 8 phases / 2 K-tiles; counted vmcnt(4)
// at phases 4 and 8 only; last iter drains with vmcnt(0).
__global__ __launch_bounds__(512, 1) void k_gemm_qk(const u16* __restrict__ A,
    const u16* __restrict__ Bm,
    const float* __restrict__ cosT, const float* __restrict__ sinT,
    u16* __restrict__ Qh, u16* __restrict__ Kh){
  __shared__ __attribute__((aligned(16))) char smem[131072];
  char* lA0 = smem;           char* lA1 = smem + 32768;
  char* lB0 = smem + 65536;   char* lB1 = smem + 98304;

  int bid = (int)blockIdx.x;
  int wg = (bid & 7)*32 + (bid >> 3);   // XCD swizzle (256 = 8*32)
  int bm = wg >> 3, bn = wg & 7;

  int tid = threadIdx.x, wv = tid >> 6, l = tid & 63;
  int lane16 = l & 15, lg = l >> 4;
  int wm = wv >> 2, wn = wv & 3;
  int rl = l >> 3;
  int sc = ((l & 7) ^ rl) * 8;          // pre-swizzled source column (u16)

  const u16* Ag = A  + (size_t)(bm*256 + wv*8 + rl)*DM + sc;
  const u16* Bg = Bm + (size_t)(bn*256 + wv*8 + rl)*DM + sc;

  auto SG = [&](const u16* gbase, char* lbase, int h, int t){
    const u16* g = gbase + (size_t)h*128*DM + t*64;
    char* ld = lbase + h*16384 + wv*1024;
    gll16(g, ld);
    gll16(g + (size_t)64*DM, ld + 8192);
  };
  auto RD = [&](const char* base, int row, int kk) -> short8 {
    return *(const short8*)(base + row*128 + (((kk*4 + lg) ^ (row & 7)) << 4));
  };

  f32x4 acc[8][4] = {};
  short8 am[4][2], bb[4][2];
  int ra = wm*128 + lane16;
  int rb = wn*64  + lane16;

  auto MF8 = [&](int mb, int n0){
    #pragma unroll
    for (int m = 0; m < 4; ++m)
      #pragma unroll
      for (int nn = 0; nn < 2; ++nn){
        int n = n0 + nn;
        acc[mb+m][n] = mfma16(am[m][0], bb[n][0], acc[mb+m][n]);
        acc[mb+m][n] = mfma16(am[m][1], bb[n][1], acc[mb+m][n]);
      }
  };

  // prologue: B0(0),A0(0),B1(1); newest 4 may stay outstanding
  SG(Bg,lB0,0,0); SG(Bg,lB0,1,0); SG(Ag,lA0,0,0); SG(Ag,lA0,1,0);
  SG(Bg,lB1,0,1); SG(Bg,lB1,1,1);
  asm volatile("s_waitcnt vmcnt(4)" ::: "memory");
  BARRIER;

  #pragma unroll 1
  for (int i = 0; i < 8; ++i){
    bool last = (i == 7);
    int t1 = 2*i + 1;
    // ---- phase 1: tile 2i Q0 (m0-3 x n0-1) ----
    #pragma unroll
    for (int m = 0; m < 4; ++m){ am[m][0]=RD(lA0, ra+m*16, 0); am[m][1]=RD(lA0, ra+m*16, 1); }
    #pragma unroll
    for (int n = 0; n < 2; ++n){ bb[n][0]=RD(lB0, rb+n*16, 0); bb[n][1]=RD(lB0, rb+n*16, 1); }
    SG(Ag, lA1, 0, t1);
    BARRIER; LGKM0;
    __builtin_amdgcn_s_setprio(1); MF8(0,0); __builtin_amdgcn_s_setprio(0);
    BARRIER;
    // ---- phase 2: Q1 (m0-3 x n2-3) ----
    #pragma unroll
    for (int n = 2; n < 4; ++n){ bb[n][0]=RD(lB0, rb+n*16, 0); bb[n][1]=RD(lB0, rb+n*16, 1); }
    SG(Ag, lA1, 1, t1);
    BARRIER; LGKM0;
    __builtin_amdgcn_s_setprio(1); MF8(0,2); __builtin_amdgcn_s_setprio(0);
    BARRIER;
    // ---- phase 3: Q2 (m4-7 x n0-1) ----
    #pragma unroll
    for (int m = 0; m < 4; ++m){ am[m][0]=RD(lA0, ra+64+m*16, 0); am[m][1]=RD(lA0, ra+64+m*16, 1); }
    if (!last) SG(Bg, lB0, 0, 2*i+2);
    BARRIER; LGKM0;
    __builtin_amdgcn_s_setprio(1); MF8(4,0); __builtin_amdgcn_s_setprio(0);
    BARRIER;
    // ---- phase 4: Q3 (m4-7 x n2-3), vmcnt covers tile 2i+1 ----
    if (!last) SG(Bg, lB0, 1, 2*i+2);
    if (last) asm volatile("s_waitcnt vmcnt(0)" ::: "memory");
    else      asm volatile("s_waitcnt vmcnt(4)" ::: "memory");
    BARRIER;
    __builtin_amdgcn_s_setprio(1); MF8(4,2); __builtin_amdgcn_s_setprio(0);
    BARRIER;
    // ---- phase 5: tile 2i+1 Q0 ----
    #pragma unroll
    for (int m = 0; m < 4; ++m){ am[m][0]=RD(lA1, ra+m*16, 0); am[m][1]=RD(lA1, ra+m*16, 1); }
    #pragma unroll
    for (int n = 0; n < 2; ++n){ bb[n][0]=RD(lB1, rb+n*16, 0); bb[n][1]=RD(lB1, rb+n*16, 1); }
    if (!last) SG(Ag, lA0, 0, 2*i+2);
    BARRIER; LGKM0;
    __builtin_amdgcn_s_setprio(1); MF8(0,0); __builtin_amdgcn_s_setprio(0);
    BARRIER;
    // ---- phase 6: Q1 ----
    #pragma unroll
    for (int n = 2; n < 4; ++n){ bb[n][0]=RD(lB1, rb+n*16, 0); bb[n][1]=RD(lB1, rb+n*16, 1); }
    if (!last) SG(Ag, lA0, 1, 2*i+2);
    BARRIER; LGKM0;
    __builtin_amdgcn_s_setprio(1); MF8(0,2); __builtin_amdgcn_s_setprio(0);
    BARRIER;
    // ---- phase 7: Q2 ----
    #pragma unroll
    for (int m = 0; m < 4; ++m){ am[m][0]=RD(lA1, ra+64+m*16, 0); am[m][1]=RD(lA1, ra+64+m*16, 1); }
    if (!last) SG(Bg, lB1, 0, 2*i+3);
    BARRIER; LGKM0;
    __builtin_amdgcn_s_setprio(1); MF8(4,0); __builtin_amdgcn_s_setprio(0);
    BARRIER;
    // ---- phase 8: Q3, vmcnt covers tile 2i+2 ----
    if (!last){
      SG(Bg, lB1, 1, 2*i+3);
      asm volatile("s_waitcnt vmcnt(4)" ::: "memory");
    }
    BARRIER;
    __builtin_amdgcn_s_setprio(1); MF8(4,2); __builtin_amdgcn_s_setprio(0);
    BARRIER;
  }

  // ---------------- RoPE epilogue (q/k; pair d<->d+32 = acc n<->n+2, same lane) ----
  int sect = bn >> 2;                 // 0=q, 1=k
  int b2  = (bm*256) >> 11;           // batch
  int ttb = (bm*256) & 2047;          // seq offset of tile
  u16* dst = sect ? Kh : Qh;
  float scq = sect ? 1.0f : 0.18033688011f;     // (1/8)*log2(e) folded into Q
  int h = (bn & 3)*4 + wn;                      // whole wave in one head
  size_t hrow = (size_t)(b2*NH + h)*T_;
  #pragma unroll
  for (int m = 0; m < 8; ++m){
    #pragma unroll
    for (int r = 0; r < 4; ++r){
      int t = ttb + wm*128 + m*16 + lg*4 + r;
      const float* cp = cosT + (size_t)t*64;
      const float* sp = sinT + (size_t)t*64;
      float c0 = cp[lane16],      s0 = sp[lane16];
      float c1 = cp[16 + lane16], s1 = sp[16 + lane16];
      float a0 = acc[m][0][r], a1 = acc[m][1][r];
      float a2 = acc[m][2][r], a3 = acc[m][3][r];
      size_t base = (hrow + t)*64;
      dst[base + lane16]      = f2b((a0*c0 - a2*s0)*scq);
      dst[base + 16 + lane16] = f2b((a1*c1 - a3*s1)*scq);
      dst[base + 32 + lane16] = f2b((a2*c0 + a0*s0)*scq);
      dst[base + 48 + lane16] = f2b((a3*c1 + a1*s1)*scq);
    }
  }
}

// ---------------- causal flash attention ----------------
// V layout is now Vt[h][d][b*T + t] (direct output of the transposed V-GEMM,
// d-row stride = B*T). 2-buffer depth-1 pipeline; in-register P via cvt_pk +
// permlane swaps (distinct-value operands only!); defer-max; exp2 softmax.
__global__ __launch_bounds__(256, 4) void k_attn(const u16* __restrict__ Qh,
    const u16* __restrict__ Kh, const u16* __restrict__ Vt, u16* __restrict__ AO){
  __shared__ __attribute__((aligned(16))) u16 lK[2][64*64];
  __shared__ __attribute__((aligned(16))) u16 lV[2][64*64];

  // bid bits: [2:0]=bh_lo (XCD), [5:3]=bh_hi, [10:6]=31-qt
  int bid = (int)blockIdx.x;
  int qt = 31 - (bid >> 6);
  int bh = ((bid >> 3) & 7) * 8 + (bid & 7);
  int q0 = qt*64;
  int b = bh >> 4, h = bh & 15;
  int tid = threadIdx.x, wv = tid >> 6, l = tid & 63;
  int lane16 = l & 15, lg = l >> 4;

  short8 bq[2];
  const u16* qp = Qh + ((size_t)bh*T_ + q0 + wv*16 + lane16)*64 + lg*8;
  bq[0] = *(const short8*)qp;
  bq[1] = *(const short8*)(qp + 32);

  f32x4 o[4] = {};
  float mrow = -INFINITY, lsum = 0.f;

  const u16* Kb = Kh + (size_t)bh*T_*64;
  const u16* Vb = Vt + (size_t)h*64*BT_ + (size_t)b*T_;   // row d stride = BT_

  int rl = l >> 3;
  int sc = ((l&7) ^ rl) * 8;
  int nt = qt + 1;

  auto STAGE = [&](int tile, int bufi){
    char* kd = (char*)lK[bufi] + wv*1024;
    char* vd = (char*)lV[bufi] + wv*1024;
    const u16* kg = Kb + (size_t)(tile*64 + wv*8 + rl)*64 + sc;
    const u16* vg = Vb + (size_t)(wv*8 + rl)*BT_ + tile*64 + sc;
    gll16(kg, kd);
    gll16(vg, vd);
    gll16(kg + 32*64, kd + 4096);
    gll16(vg + (size_t)32*BT_, vd + 4096);
  };

  STAGE(0, 0);

  for (int it = 0; it < nt; ++it){
    int cur = it & 1;
    asm volatile("s_waitcnt vmcnt(0)" ::: "memory");
    __builtin_amdgcn_s_barrier();
    if (it + 1 < nt) STAGE(it + 1, cur ^ 1);

    const char* Kc = (const char*)lK[cur];
    const char* Vc = (const char*)lV[cur];
    int kv0 = it*64;

    f32x4 s[4];
    __builtin_amdgcn_s_setprio(1);
    #pragma unroll
    for (int n = 0; n < 4; ++n){
      int row = n*16 + lane16;
      short8 ak0 = *(const short8*)(Kc + row*128 + (((lg    ) ^ (row&7))<<4));
      short8 ak1 = *(const short8*)(Kc + row*128 + (((4 + lg) ^ (row&7))<<4));
      f32x4 z = {};
      z = mfma16(ak0, bq[0], z);
      z = mfma16(ak1, bq[1], z);
      s[n] = z;
    }
    __builtin_amdgcn_s_setprio(0);

    if (it == nt-1){
      int q_abs = q0 + wv*16 + lane16;
      #pragma unroll
      for (int n = 0; n < 4; ++n)
        #pragma unroll
        for (int r = 0; r < 4; ++r){
          int key = kv0 + n*16 + lg*4 + r;
          if (key > q_abs) s[n][r] = -1e30f;
        }
    }

    float pm = s[0][0];
    #pragma unroll
    for (int n = 0; n < 4; ++n)
      #pragma unroll
      for (int r = 0; r < 4; ++r) pm = fmaxf(pm, s[n][r]);
    pm = fmaxf(pm, __shfl_xor(pm, 16, 64));
    pm = fmaxf(pm, __shfl_xor(pm, 32, 64));

    if (__any(pm > mrow + 8.f)){
      float mn = fmaxf(mrow, pm);
      float al = __builtin_amdgcn_exp2f(mrow - mn);
      mrow = mn;
      float alr[4];
      #pragma unroll
      for (int r = 0; r < 4; ++r) alr[r] = __shfl(al, (l & 48) | (lg*4 + r), 64);
      #pragma unroll
      for (int dn = 0; dn < 4; ++dn)
        #pragma unroll
        for (int r = 0; r < 4; ++r) o[dn][r] *= alr[r];
      lsum *= al;
    }

    float rs = 0.f;
    #pragma unroll
    for (int n = 0; n < 4; ++n)
      #pragma unroll
      for (int r = 0; r < 4; ++r){
        float p = __builtin_amdgcn_exp2f(s[n][r] - mrow);
        s[n][r] = p; rs += p;
      }
    lsum += rs;

    unsigned d[4][2];
    #pragma unroll
    for (int n = 0; n < 4; ++n){
      asm("v_cvt_pk_bf16_f32 %0, %1, %2" : "=v"(d[n][0]) : "v"(s[n][0]), "v"(s[n][1]));
      asm("v_cvt_pk_bf16_f32 %0, %1, %2" : "=v"(d[n][1]) : "v"(s[n][2]), "v"(s[n][3]));
    }
    union { unsigned u[4]; short8 v; } pk0, pk1;
    #pragma unroll
    for (int g = 0; g < 2; ++g){
      #pragma unroll
      for (int hh = 0; hh < 2; ++hh){
        unsigned A = d[2*g][hh], Bv = d[2*g+1][hh];
        asm("v_permlane32_swap_b32 %0, %1" : "+v"(A), "+v"(Bv));
        asm("v_permlane16_swap_b32 %0, %1" : "+v"(A), "+v"(Bv));
        if (g == 0){ pk0.u[hh] = A; pk0.u[2+hh] = Bv; }
        else       { pk1.u[hh] = A; pk1.u[2+hh] = Bv; }
      }
    }

    __builtin_amdgcn_s_setprio(1);
    #pragma unroll
    for (int dn = 0; dn < 4; ++dn){
      int row = dn*16 + lane16;
      short8 bv0 = *(const short8*)(Vc + row*128 + (((lg    ) ^ (row&7))<<4));
      short8 bv1 = *(const short8*)(Vc + row*128 + (((4 + lg) ^ (row&7))<<4));
      o[dn] = mfma16(pk0.v, bv0, o[dn]);
      o[dn] = mfma16(pk1.v, bv1, o[dn]);
    }
    __builtin_amdgcn_s_setprio(0);
  }

  lsum += __shfl_xor(lsum, 16, 64);
  lsum += __shfl_xor(lsum, 32, 64);
  float inv = 1.f / lsum;
  float ivr[4];
  #pragma unroll
  for (int r = 0; r < 4; ++r) ivr[r] = __shfl(inv, (l & 48) | (lg*4 + r), 64);
  #pragma unroll
  for (int r = 0; r < 4; ++r){
    int t = q0 + wv*16 + lg*4 + r;
    #pragma unroll
    for (int dn = 0; dn < 4; ++dn)
      AO[((size_t)(b*T_ + t))*DM + h*64 + dn*16 + lane16] = f2b(o[dn][r]*ivr[r]);
  }
}

// ---------------- launch ----------------
extern "C" void kernel_launch(void* const* d_in, const int* in_sizes, int n_in,
                              void* d_out, int out_size, void* d_ws, size_t ws_size,
                              hipStream_t stream) {
  const float* x     = (const float*)d_in[0];
  const float* cosT  = (const float*)d_in[1];
  const float* sinT  = (const float*)d_in[2];
  const float* w_qkv = (const float*)d_in[3];
  const float* w_out = (const float*)d_in[4];
  float* out = (float*)d_out;

  char* ws = (char*)d_ws;
  u16* xb    = (u16*)(ws);                      // 16 MB  (8192x1024 bf16)
  u16* wqkvb = (u16*)(ws + 16777216);           // 6 MB   (3072x1024)
  u16* woutb = (u16*)(ws + 23068672);           // 2 MB   (1024x1024)
  u16* AO    = (u16*)(ws + 25165824);           // 16 MB  (8192x1024)
  u16* Kh    = (u16*)(ws + 41943040);           // 16 MB  [BH][T][64]
  u16* Vt    = (u16*)(ws + 58720256);           // 16 MB  [H][64][B*T]
  u16* Qh    = (u16*)(ws + 75497472);           // 16 MB  -> total 88 MB

  // 1) convert all inputs to bf16 (single fused launch)
  k_f2b3<<<(N8_X+N8_WQ+N8_WO)/256, 256, 0, stream>>>(x, w_qkv, w_out, xb, wqkvb, woutb);

  // 2a) Q|K GEMM (256^2 8-phase, 256 blocks = exactly 1 pass) + RoPE epilogue
  k_gemm_qk<<<256, 512, 0, stream>>>(xb, wqkvb, cosT, sinT, Qh, Kh);

  // 2b) V as transposed GEMM: Vt = Wv @ x^T  (M=1024, N=8192; 512 blocks = 1 pass
  //     at 2 blocks/CU; backfills CUs as 2a retires). Output layout IS Vt.
  k_gemm_bt<u16><<<512, 256, 0, stream>>>(wqkvb + (size_t)2*DM*DM, xb, Vt, DM, BT_, DM);

  // 3) causal flash attention -> AO [B,T,DM] bf16
  k_attn<<<2048, 256, 0, stream>>>(Qh, Kh, Vt, AO);

  // 4) out = AO @ w_out^T  (f32 out)
  k_gemm_bt<float><<<(BT_/128)*(DM/128), 256, 0, stream>>>(AO, woutb, out, BT_, DM, DM);
}